// Round 10
// baseline (1176.158 us; speedup 1.0000x reference)
//
#include <hip/hip_runtime.h>
#include <hip/hip_bf16.h>

#define N_CELLS  200000
#define N_FACES  400000
#define N_POINTS 200000
#define E_CF     800000
#define E_FP     800000
#define E_PP     1200000
#define E_TOT    2800000
#define NROWS    800000    // N_FACES + N_POINTS + N_POINTS (concatenated)
#define FP_BASE  400000
#define PP_BASE  600000
#define BSHIFT   11        // 2048 rows per bucket
#define NB       391       // ceil(800000/2048)
#define SUBCAP   2048      // records per (bucket,xcd); expected <=1536
#define HWREG_XCC_ID 14356 // (size8-1)<<11 | 0<<6 | id20

typedef __attribute__((ext_vector_type(8))) short bf16x8;
typedef __attribute__((ext_vector_type(8))) unsigned short u16x8;
typedef __attribute__((ext_vector_type(4))) float f32x4;

__device__ __forceinline__ float bf2f(unsigned short u) {
    union { unsigned int i; float f; } v; v.i = ((unsigned int)u) << 16; return v.f;
}
__device__ __forceinline__ unsigned short f2bf(float f) {
    __hip_bfloat16 h = __float2bfloat16(f);
    return *reinterpret_cast<unsigned short*>(&h);
}

// ======== fused: zero cnt + zero scur + pack W_fp + pack [W_rt;W_pp] ========
__global__ __launch_bounds__(256) void k_pre(int* __restrict__ cnt,
                                             int* __restrict__ scur,
                                             const float* __restrict__ W_fp,
                                             const float* __restrict__ W_rt,
                                             const float* __restrict__ W_pp,
                                             unsigned short* __restrict__ Bp_fp,
                                             unsigned short* __restrict__ Bp_fin) {
    int b = blockIdx.x;
    if (b < 3125) {
        int t = b * 256 + threadIdx.x;
        if (t < NROWS) cnt[t] = 0;
    } else if (b == 3125) {
        for (int i = threadIdx.x; i < NB * 8; i += 256) scur[i] = 0;
    } else if (b < 3174) {                        // pack W_fp: 48 blocks
        int t = (b - 3126) * 256 + threadIdx.x;   // 12288
        int j = t & 7, lane = (t >> 3) & 63, ct = (t >> 9) & 7, ks = t >> 12;
        int k = ks * 32 + ((lane >> 4) & 3) * 8 + j;
        int col = ct * 16 + (lane & 15);
        Bp_fp[t] = f2bf(W_fp[k * 128 + col]);
    } else {                                      // pack fin: 128 blocks
        int t = (b - 3174) * 256 + threadIdx.x;   // 32768
        int j = t & 7, lane = (t >> 3) & 63, ct = (t >> 9) & 7, ks = t >> 12;
        int k = ks * 32 + ((lane >> 4) & 3) * 8 + j;   // 0..255
        int col = ct * 16 + (lane & 15);
        float v = (k < 128) ? W_rt[k * 128 + col] : W_pp[(k - 128) * 128 + col];
        Bp_fin[t] = f2bf(v);
    }
}

// ======== pass A: bin records into per-(bucket,XCD) staging + histogram ========
__device__ __forceinline__ void binA(const int* __restrict__ src,
                                     const int* __restrict__ dst,
                                     const float* __restrict__ ea,
                                     int nE, int base, int tid0, int stride, int xcd,
                                     int* __restrict__ cnt,
                                     int* __restrict__ scur,
                                     int2* __restrict__ stg) {
    for (int e = tid0; e < nE; e += stride) {
        int4 d4 = *(const int4*)(dst + e);
        int4 s4 = *(const int4*)(src + e);
        float4 w4 = *(const float4*)(ea + e);
        int dd[4] = {d4.x + base, d4.y + base, d4.z + base, d4.w + base};
        int ss[4] = {s4.x, s4.y, s4.z, s4.w};
        float ww[4] = {w4.x, w4.y, w4.z, w4.w};
#pragma unroll
        for (int i = 0; i < 4; ++i) {
            int d = dd[i];
            atomicAdd(&cnt[d], 1);
            int bk = d >> BSHIFT;
            int t = atomicAdd(&scur[bk * 8 + xcd], 1);
            if (t < SUBCAP) {
                int lo = ((d - (bk << BSHIFT)) << 19) | ss[i];
                stg[(size_t)(bk * 8 + xcd) * SUBCAP + t] = make_int2(lo, __float_as_int(ww[i]));
            }
        }
    }
}

__global__ __launch_bounds__(256) void k_passA(const int* __restrict__ src_cf,
                                               const int* __restrict__ dst_cf,
                                               const float* __restrict__ ea_cf,
                                               const int* __restrict__ src_fp,
                                               const int* __restrict__ dst_fp,
                                               const float* __restrict__ ea_fp,
                                               const int* __restrict__ src_pp,
                                               const int* __restrict__ dst_pp,
                                               const float* __restrict__ ea_pp,
                                               int* __restrict__ cnt,
                                               int* __restrict__ scur,
                                               int2* __restrict__ stg) {
    int xcd = (int)(__builtin_amdgcn_s_getreg(HWREG_XCC_ID) & 7u);
    int tid0 = (blockIdx.x * 256 + (int)threadIdx.x) * 4;
    const int stride = 1024 * 256 * 4;
    binA(src_cf, dst_cf, ea_cf, E_CF, 0,       tid0, stride, xcd, cnt, scur, stg);
    binA(src_fp, dst_fp, ea_fp, E_FP, FP_BASE, tid0, stride, xcd, cnt, scur, stg);
    binA(src_pp, dst_pp, ea_pp, E_PP, PP_BASE, tid0, stride, xcd, cnt, scur, stg);
}

// ======== scans over 800k counts (2048/block) ========
__global__ __launch_bounds__(256) void k_scan1(const int* __restrict__ cnt,
                                               int* __restrict__ bsum) {
    __shared__ int sh[256];
    int base = blockIdx.x * 2048 + threadIdx.x * 8;
    int s = 0;
#pragma unroll
    for (int i = 0; i < 8; ++i) { int idx = base + i; if (idx < NROWS) s += cnt[idx]; }
    sh[threadIdx.x] = s;
    __syncthreads();
    for (int off = 128; off > 0; off >>= 1) {
        if (threadIdx.x < off) sh[threadIdx.x] += sh[threadIdx.x + off];
        __syncthreads();
    }
    if (threadIdx.x == 0) bsum[blockIdx.x] = sh[0];
}

__global__ __launch_bounds__(512) void k_scan2(int* __restrict__ bsum, int nb) {
    __shared__ int sh[512];
    int t = threadIdx.x;
    int v = (t < nb) ? bsum[t] : 0;
    sh[t] = v;
    __syncthreads();
    for (int off = 1; off < 512; off <<= 1) {
        int add = (t >= off) ? sh[t - off] : 0;
        __syncthreads();
        sh[t] += add;
        __syncthreads();
    }
    if (t < nb) bsum[t] = sh[t] - v;
}

__global__ __launch_bounds__(256) void k_scan3(const int* __restrict__ cnt,
                                               const int* __restrict__ bsum,
                                               int* __restrict__ rowptr,
                                               int* __restrict__ cur) {
    __shared__ int sh[256];
    int base = blockIdx.x * 2048 + threadIdx.x * 8;
    int c[8]; int s = 0;
#pragma unroll
    for (int i = 0; i < 8; ++i) { int idx = base + i; c[i] = (idx < NROWS) ? cnt[idx] : 0; s += c[i]; }
    sh[threadIdx.x] = s;
    __syncthreads();
    int v = s;
    for (int off = 1; off < 256; off <<= 1) {
        int add = (threadIdx.x >= off) ? sh[threadIdx.x - off] : 0;
        __syncthreads();
        sh[threadIdx.x] += add;
        __syncthreads();
    }
    int excl = sh[threadIdx.x] - v + bsum[blockIdx.x];
#pragma unroll
    for (int i = 0; i < 8; ++i) {
        int idx = base + i;
        if (idx < NROWS) {
            rowptr[idx] = excl; cur[idx] = excl; excl += c[i];
            if (idx == NROWS - 1) rowptr[NROWS] = excl;
        }
    }
}

// ======== pass B: staged records -> exact CSR slots (L2-local per bucket) ========
__global__ __launch_bounds__(256) void k_passB(const int2* __restrict__ stg,
                                               const int* __restrict__ scur,
                                               int* __restrict__ cur,
                                               int2* __restrict__ pe) {
    int b = blockIdx.x >> 1;
    int x0 = (blockIdx.x & 1) * 4;
    int baser = b << BSHIFT;
    for (int x = x0; x < x0 + 4; ++x) {
        int n = scur[b * 8 + x];
        if (n > SUBCAP) n = SUBCAP;
        const int2* s = stg + (size_t)(b * 8 + x) * SUBCAP;
        for (int i = threadIdx.x; i < n; i += 256) {
            int2 r = s[i];
            unsigned lo = (unsigned)r.x;
            int d = baser + (int)(lo >> 19);
            int slot = atomicAdd(&cur[d], 1);
            pe[slot] = make_int2((int)(lo & 0x7FFFFu), r.y);
        }
    }
}

// ======== fused gather(cells->faces) + transform + concat ========
__global__ __launch_bounds__(256) void k_gather8_tf(const float* __restrict__ xc,
                                                    const int* __restrict__ ptr,
                                                    const int2* __restrict__ pe,
                                                    const float* __restrict__ x_face,
                                                    const float* __restrict__ W,
                                                    const float* __restrict__ b,
                                                    unsigned short* __restrict__ yfp) {
    __shared__ float Ws[512];
    __shared__ float bs[64];
    for (int i = threadIdx.x; i < 512; i += 256) Ws[i] = W[i];
    if (threadIdx.x < 64) bs[threadIdx.x] = b[threadIdx.x];
    __syncthreads();
    int r = blockIdx.x * 256 + threadIdx.x;
    if (r >= N_FACES) return;
    int e = ptr[r], end = ptr[r + 1];
    float a[8] = {};
    for (; e + 1 < end; e += 2) {
        int2 q0 = pe[e], q1 = pe[e + 1];
        float w0 = __int_as_float(q0.y), w1 = __int_as_float(q1.y);
        const float* p0 = xc + (size_t)q0.x * 8;
        const float* p1 = xc + (size_t)q1.x * 8;
        float4 u0 = *(const float4*)p0, u1 = *(const float4*)(p0 + 4);
        float4 v0 = *(const float4*)p1, v1 = *(const float4*)(p1 + 4);
        a[0] += w0 * u0.x + w1 * v0.x; a[1] += w0 * u0.y + w1 * v0.y;
        a[2] += w0 * u0.z + w1 * v0.z; a[3] += w0 * u0.w + w1 * v0.w;
        a[4] += w0 * u1.x + w1 * v1.x; a[5] += w0 * u1.y + w1 * v1.y;
        a[6] += w0 * u1.z + w1 * v1.z; a[7] += w0 * u1.w + w1 * v1.w;
    }
    if (e < end) {
        int2 q0 = pe[e];
        float w0 = __int_as_float(q0.y);
        const float* p0 = xc + (size_t)q0.x * 8;
        float4 u0 = *(const float4*)p0, u1 = *(const float4*)(p0 + 4);
        a[0] += w0 * u0.x; a[1] += w0 * u0.y; a[2] += w0 * u0.z; a[3] += w0 * u0.w;
        a[4] += w0 * u1.x; a[5] += w0 * u1.y; a[6] += w0 * u1.z; a[7] += w0 * u1.w;
    }
    unsigned short* orow = yfp + (size_t)r * 96;
#pragma unroll
    for (int c4 = 0; c4 < 4; ++c4) {
        int j0 = c4 * 16;
        float acc[16];
#pragma unroll
        for (int i = 0; i < 16; ++i) acc[i] = bs[j0 + i];
#pragma unroll
        for (int k = 0; k < 8; ++k) {
            float x = a[k];
            const float* wr = Ws + k * 64 + j0;
#pragma unroll
            for (int i = 0; i < 16; ++i) acc[i] += x * wr[i];
        }
        u16x8 o0, o1;
#pragma unroll
        for (int i = 0; i < 8; ++i) { o0[i] = f2bf(acc[i]); o1[i] = f2bf(acc[8 + i]); }
        *(u16x8*)(orow + j0) = o0;
        *(u16x8*)(orow + j0 + 8) = o1;
    }
    float4 xf0 = *(const float4*)(x_face + (size_t)r * 8);
    float4 xf1 = *(const float4*)(x_face + (size_t)r * 8 + 4);
    u16x8 xo;
    xo[0] = f2bf(xf0.x); xo[1] = f2bf(xf0.y); xo[2] = f2bf(xf0.z); xo[3] = f2bf(xf0.w);
    xo[4] = f2bf(xf1.x); xo[5] = f2bf(xf1.y); xo[6] = f2bf(xf1.z); xo[7] = f2bf(xf1.w);
    *(u16x8*)(orow + 64) = xo;
}

// ======== faces->points gather (96 bf16 cols): 2 rows/wave, 4-deep ========
__global__ __launch_bounds__(256) void k_gather96(const unsigned short* __restrict__ feat,
                                                  const int* __restrict__ ptr,
                                                  const int2* __restrict__ pe,
                                                  unsigned short* __restrict__ aggf, int nRows) {
    int gw = (blockIdx.x * 256 + threadIdx.x) >> 6;
    int lane = threadIdx.x & 63;
    int row = gw * 2 + (lane >> 5);
    int l = lane & 31;
    if (row >= nRows) return;
    int e = ptr[row], end = ptr[row + 1];
    float a0 = 0.f, a1 = 0.f, a2 = 0.f;
    for (; e + 3 < end; e += 4) {
        int2 q0 = pe[e], q1 = pe[e + 1], q2 = pe[e + 2], q3 = pe[e + 3];
        float w0 = __int_as_float(q0.y), w1 = __int_as_float(q1.y);
        float w2 = __int_as_float(q2.y), w3 = __int_as_float(q3.y);
        const unsigned short* f0 = feat + (size_t)q0.x * 96 + l;
        const unsigned short* f1 = feat + (size_t)q1.x * 96 + l;
        const unsigned short* f2 = feat + (size_t)q2.x * 96 + l;
        const unsigned short* f3 = feat + (size_t)q3.x * 96 + l;
        a0 += w0 * bf2f(f0[0])  + w1 * bf2f(f1[0])  + w2 * bf2f(f2[0])  + w3 * bf2f(f3[0]);
        a1 += w0 * bf2f(f0[32]) + w1 * bf2f(f1[32]) + w2 * bf2f(f2[32]) + w3 * bf2f(f3[32]);
        a2 += w0 * bf2f(f0[64]) + w1 * bf2f(f1[64]) + w2 * bf2f(f2[64]) + w3 * bf2f(f3[64]);
    }
    for (; e < end; ++e) {
        int2 q0 = pe[e];
        float w0 = __int_as_float(q0.y);
        const unsigned short* f0 = feat + (size_t)q0.x * 96 + l;
        a0 += w0 * bf2f(f0[0]); a1 += w0 * bf2f(f0[32]); a2 += w0 * bf2f(f0[64]);
    }
    unsigned short* o = aggf + (size_t)row * 96 + l;
    o[0] = f2bf(a0); o[32] = f2bf(a1); o[64] = f2bf(a2);
}

// ======== points->points gather (128 bf16 cols): 2 rows/wave, 4-deep ========
__global__ __launch_bounds__(256) void k_gather128pp(const unsigned short* __restrict__ feat,
                                                     const int* __restrict__ ptr,
                                                     const int2* __restrict__ pe,
                                                     unsigned short* __restrict__ aggp, int nRows) {
    int gw = (blockIdx.x * 256 + threadIdx.x) >> 6;
    int lane = threadIdx.x & 63;
    int row = gw * 2 + (lane >> 5);
    int l = lane & 31;
    if (row >= nRows) return;
    int e = ptr[row], end = ptr[row + 1];
    float a0 = 0.f, a1 = 0.f, a2 = 0.f, a3 = 0.f;
    for (; e + 3 < end; e += 4) {
        int2 q0 = pe[e], q1 = pe[e + 1], q2 = pe[e + 2], q3 = pe[e + 3];
        float w0 = __int_as_float(q0.y), w1 = __int_as_float(q1.y);
        float w2 = __int_as_float(q2.y), w3 = __int_as_float(q3.y);
        const unsigned short* f0 = feat + ((size_t)q0.x << 7) + l;
        const unsigned short* f1 = feat + ((size_t)q1.x << 7) + l;
        const unsigned short* f2 = feat + ((size_t)q2.x << 7) + l;
        const unsigned short* f3 = feat + ((size_t)q3.x << 7) + l;
        a0 += w0 * bf2f(f0[0])  + w1 * bf2f(f1[0])  + w2 * bf2f(f2[0])  + w3 * bf2f(f3[0]);
        a1 += w0 * bf2f(f0[32]) + w1 * bf2f(f1[32]) + w2 * bf2f(f2[32]) + w3 * bf2f(f3[32]);
        a2 += w0 * bf2f(f0[64]) + w1 * bf2f(f1[64]) + w2 * bf2f(f2[64]) + w3 * bf2f(f3[64]);
        a3 += w0 * bf2f(f0[96]) + w1 * bf2f(f1[96]) + w2 * bf2f(f2[96]) + w3 * bf2f(f3[96]);
    }
    for (; e < end; ++e) {
        int2 q0 = pe[e];
        float w0 = __int_as_float(q0.y);
        const unsigned short* f0 = feat + ((size_t)q0.x << 7) + l;
        a0 += w0 * bf2f(f0[0]);  a1 += w0 * bf2f(f0[32]);
        a2 += w0 * bf2f(f0[64]); a3 += w0 * bf2f(f0[96]);
    }
    unsigned short* o = aggp + ((size_t)row << 7) + l;
    o[0] = f2bf(a0); o[32] = f2bf(a1); o[64] = f2bf(a2); o[96] = f2bf(a3);
}

// ======== MFMA: y_ptb = bf16(aggf[200k,96] @ W_fp + b_fp) ========
__global__ __launch_bounds__(256) void k_mfma96(const unsigned short* __restrict__ A,
                                                const unsigned short* __restrict__ Bp,
                                                const float* __restrict__ bias,
                                                unsigned short* __restrict__ O) {
    const int w = threadIdx.x >> 6;
    const int lane = threadIdx.x & 63;
    const int rg = w >> 1, cg = w & 1;
    const int row0 = blockIdx.x * 32 + rg * 16;
    bf16x8 bfr[3][4];
#pragma unroll
    for (int ks = 0; ks < 3; ++ks)
#pragma unroll
        for (int c = 0; c < 4; ++c) {
            int ct = cg * 4 + c;
            bfr[ks][c] = *(const bf16x8*)(Bp + ((size_t)(ks * 8 + ct) * 64 + lane) * 8);
        }
    f32x4 acc[4] = {};
    const unsigned short* arow = A + (size_t)(row0 + (lane & 15)) * 96 + ((lane >> 4) * 8);
#pragma unroll
    for (int ks = 0; ks < 3; ++ks) {
        bf16x8 af = *(const bf16x8*)(arow + ks * 32);
#pragma unroll
        for (int c = 0; c < 4; ++c)
            acc[c] = __builtin_amdgcn_mfma_f32_16x16x32_bf16(af, bfr[ks][c], acc[c], 0, 0, 0);
    }
    const int rbase = row0 + (lane >> 4) * 4;
#pragma unroll
    for (int c = 0; c < 4; ++c) {
        int gcol = cg * 64 + c * 16 + (lane & 15);
        float bv = bias[gcol];
#pragma unroll
        for (int r = 0; r < 4; ++r)
            O[(size_t)(rbase + r) * 128 + gcol] = f2bf(acc[c][r] + bv);
    }
}

// ======== MFMA: out = [y_ptb | aggp] @ [W_rt;W_pp] + b_pp ========
__global__ __launch_bounds__(256) void k_mfma_fin(const unsigned short* __restrict__ A1,
                                                  const unsigned short* __restrict__ A2,
                                                  const unsigned short* __restrict__ Bp,
                                                  const float* __restrict__ bias,
                                                  float* __restrict__ out) {
    const int w = threadIdx.x >> 6;
    const int lane = threadIdx.x & 63;
    const int rg = w >> 1, cg = w & 1;
    const int row0 = blockIdx.x * 32 + rg * 16;
    bf16x8 bfr[8][4];
#pragma unroll
    for (int ks = 0; ks < 8; ++ks)
#pragma unroll
        for (int c = 0; c < 4; ++c) {
            int ct = cg * 4 + c;
            bfr[ks][c] = *(const bf16x8*)(Bp + ((size_t)(ks * 8 + ct) * 64 + lane) * 8);
        }
    f32x4 acc[4] = {};
    const unsigned short* a1 = A1 + (size_t)(row0 + (lane & 15)) * 128 + ((lane >> 4) * 8);
    const unsigned short* a2 = A2 + (size_t)(row0 + (lane & 15)) * 128 + ((lane >> 4) * 8);
#pragma unroll
    for (int ks = 0; ks < 4; ++ks) {
        bf16x8 af = *(const bf16x8*)(a1 + ks * 32);
#pragma unroll
        for (int c = 0; c < 4; ++c)
            acc[c] = __builtin_amdgcn_mfma_f32_16x16x32_bf16(af, bfr[ks][c], acc[c], 0, 0, 0);
    }
#pragma unroll
    for (int ks = 0; ks < 4; ++ks) {
        bf16x8 af = *(const bf16x8*)(a2 + ks * 32);
#pragma unroll
        for (int c = 0; c < 4; ++c)
            acc[c] = __builtin_amdgcn_mfma_f32_16x16x32_bf16(af, bfr[ks + 4][c], acc[c], 0, 0, 0);
    }
    const int rbase = row0 + (lane >> 4) * 4;
#pragma unroll
    for (int c = 0; c < 4; ++c) {
        int gcol = cg * 64 + c * 16 + (lane & 15);
        float bv = bias[gcol];
#pragma unroll
        for (int r = 0; r < 4; ++r)
            out[(size_t)(rbase + r) * 128 + gcol] = acc[c][r] + bv;
    }
}

extern "C" void kernel_launch(void* const* d_in, const int* in_sizes, int n_in,
                              void* d_out, int out_size, void* d_ws, size_t ws_size,
                              hipStream_t stream) {
    const float* x_centers = (const float*)d_in[0];
    const float* x_face    = (const float*)d_in[1];
    const float* W_cf      = (const float*)d_in[2];
    const float* b_cf      = (const float*)d_in[3];
    const float* W_fp      = (const float*)d_in[4];
    const float* b_fp      = (const float*)d_in[5];
    const float* W_pp      = (const float*)d_in[6];
    const float* W_rt      = (const float*)d_in[7];
    const float* b_pp      = (const float*)d_in[8];
    const float* ea_cf     = (const float*)d_in[9];
    const float* ea_fp     = (const float*)d_in[10];
    const float* ea_pp     = (const float*)d_in[11];
    const int* src_cf      = (const int*)d_in[12];
    const int* dst_cf      = (const int*)d_in[13];
    const int* src_fp      = (const int*)d_in[14];
    const int* dst_fp      = (const int*)d_in[15];
    const int* src_pp      = (const int*)d_in[16];
    const int* dst_pp      = (const int*)d_in[17];
    float* out = (float*)d_out;

    char* ws = (char*)d_ws;
    unsigned short* yfp    = (unsigned short*)(ws + 0);           // bf16 [400k][96]  76.8MB
    unsigned short* aggf   = (unsigned short*)(ws + 80000000);    // bf16 [200k][96]  38.4MB
    unsigned short* y_ptb  = (unsigned short*)(ws + 120000000);   // bf16 [200k][128] 51.2MB
    unsigned short* aggp   = (unsigned short*)(ws + 172000000);   // bf16 [200k][128] 51.2MB
    int2* pe_all           = (int2*)(ws + 224000000);             // 2.8M recs 22.4MB
    int*  cnt_all          = (int*)(ws + 247000000);              // 800000 counts -> cursors
    int*  ptr_all          = (int*)(ws + 251000000);              // 800001 rowptr
    int*  bsum             = (int*)(ws + 255000000);              // 391
    unsigned short* Bp_fp  = (unsigned short*)(ws + 255100000);   // 24KB
    unsigned short* Bp_fin = (unsigned short*)(ws + 255200000);   // 64KB
    int2* stg              = (int2*)(ws + 256000000);             // 391*8*2048*8B = 51.25MB
    int*  scur             = (int*)(ws + 308000000);              // 391*8 ints

    // CSR build: zero+pack -> binA(+hist) -> scans -> passB
    k_pre<<<3302, 256, 0, stream>>>(cnt_all, scur, W_fp, W_rt, W_pp, Bp_fp, Bp_fin);
    k_passA<<<1024, 256, 0, stream>>>(src_cf, dst_cf, ea_cf, src_fp, dst_fp, ea_fp,
                                      src_pp, dst_pp, ea_pp, cnt_all, scur, stg);
    k_scan1<<<391, 256, 0, stream>>>(cnt_all, bsum);
    k_scan2<<<1, 512, 0, stream>>>(bsum, 391);
    k_scan3<<<391, 256, 0, stream>>>(cnt_all, bsum, ptr_all, cnt_all);
    k_passB<<<NB * 2, 256, 0, stream>>>(stg, scur, cnt_all, pe_all);
    // pipeline
    k_gather8_tf<<<1563, 256, 0, stream>>>(x_centers, ptr_all, pe_all, x_face, W_cf, b_cf, yfp);
    k_gather96<<<25000, 256, 0, stream>>>(yfp, ptr_all + FP_BASE, pe_all, aggf, N_POINTS);
    k_mfma96<<<6250, 256, 0, stream>>>(aggf, Bp_fp, b_fp, y_ptb);
    k_gather128pp<<<25000, 256, 0, stream>>>(y_ptb, ptr_all + PP_BASE, pe_all, aggp, N_POINTS);
    k_mfma_fin<<<6250, 256, 0, stream>>>(y_ptb, aggp, Bp_fin, b_pp, out);
}

// Round 11
// 601.316 us; speedup vs baseline: 1.9560x; 1.9560x over previous
//
#include <hip/hip_runtime.h>
#include <hip/hip_bf16.h>

#define N_CELLS  200000
#define N_FACES  400000
#define N_POINTS 200000
#define E_CF     800000
#define E_FP     800000
#define E_PP     1200000
#define E_TOT    2800000
#define NROWS    800000    // N_FACES + N_POINTS + N_POINTS (concatenated)
#define FP_BASE  400000
#define PP_BASE  600000
#define NBKT     64        // partition buckets (equal expected records)
#define BINCAP   96        // LDS records per bin per tile (mean <=57)
#define BCAP     65536     // staging records per bucket (mean 43750, sigma ~210)

typedef __attribute__((ext_vector_type(8))) short bf16x8;
typedef __attribute__((ext_vector_type(8))) unsigned short u16x8;
typedef __attribute__((ext_vector_type(4))) float f32x4;

__device__ __forceinline__ float bf2f(unsigned short u) {
    union { unsigned int i; float f; } v; v.i = ((unsigned int)u) << 16; return v.f;
}
__device__ __forceinline__ unsigned short f2bf(float f) {
    __hip_bfloat16 h = __float2bfloat16(f);
    return *reinterpret_cast<unsigned short*>(&h);
}

// 64 buckets, equal expected records: cf rows/22223 (18), fp rows/11112 (18), pp rows/7143 (28)
__device__ __forceinline__ int bucket_of(int d) {
    if (d < 400000) return d / 22223;
    if (d < 600000) return 18 + (d - 400000) / 11112;
    return 36 + (d - 600000) / 7143;
}

// ======== fused: zero cnt + zero scur + pack W_fp + pack [W_rt;W_pp] ========
__global__ __launch_bounds__(256) void k_pre(int* __restrict__ cnt,
                                             int* __restrict__ scur,
                                             const float* __restrict__ W_fp,
                                             const float* __restrict__ W_rt,
                                             const float* __restrict__ W_pp,
                                             unsigned short* __restrict__ Bp_fp,
                                             unsigned short* __restrict__ Bp_fin) {
    int b = blockIdx.x;
    if (b < 3125) {
        int t = b * 256 + threadIdx.x;
        if (t < NROWS) cnt[t] = 0;
    } else if (b == 3125) {
        if (threadIdx.x < NBKT) scur[threadIdx.x] = 0;
    } else if (b < 3174) {                        // pack W_fp: 48 blocks
        int t = (b - 3126) * 256 + threadIdx.x;   // 12288
        int j = t & 7, lane = (t >> 3) & 63, ct = (t >> 9) & 7, ks = t >> 12;
        int k = ks * 32 + ((lane >> 4) & 3) * 8 + j;
        int col = ct * 16 + (lane & 15);
        Bp_fp[t] = f2bf(W_fp[k * 128 + col]);
    } else {                                      // pack fin: 128 blocks
        int t = (b - 3174) * 256 + threadIdx.x;   // 32768
        int j = t & 7, lane = (t >> 3) & 63, ct = (t >> 9) & 7, ks = t >> 12;
        int k = ks * 32 + ((lane >> 4) & 3) * 8 + j;   // 0..255
        int col = ct * 16 + (lane & 15);
        float v = (k < 128) ? W_rt[k * 128 + col] : W_pp[(k - 128) * 128 + col];
        Bp_fin[t] = f2bf(v);
    }
}

// ======== pass 1: LDS-binned bucket partition + folded histogram ========
__global__ __launch_bounds__(256) void k_pass1(const int* __restrict__ src_cf,
                                               const int* __restrict__ dst_cf,
                                               const float* __restrict__ ea_cf,
                                               const int* __restrict__ src_fp,
                                               const int* __restrict__ dst_fp,
                                               const float* __restrict__ ea_fp,
                                               const int* __restrict__ src_pp,
                                               const int* __restrict__ dst_pp,
                                               const float* __restrict__ ea_pp,
                                               int* __restrict__ cnt,
                                               int* __restrict__ scur,
                                               int2* __restrict__ stg_a,
                                               int* __restrict__ stg_d) {
    __shared__ int  bcnt[NBKT];
    __shared__ int  bbase[NBKT];
    __shared__ int2 bbuf[NBKT][BINCAP];   // 48 KB
    __shared__ int  bd[NBKT][BINCAP];     // 24 KB
    if (threadIdx.x < NBKT) bcnt[threadIdx.x] = 0;
    __syncthreads();

    int e0 = (blockIdx.x * 256 + (int)threadIdx.x) * 4;
    int s_[4], d_[4]; float w_[4]; int nv = 0;
    if (e0 + 3 < E_TOT) {
        int r0 = (e0 < E_CF) ? 0 : (e0 < E_CF + E_FP ? 1 : 2);
        int r3 = (e0 + 3 < E_CF) ? 0 : (e0 + 3 < E_CF + E_FP ? 1 : 2);
        if (r0 == r3) {
            const int* sp; const int* dp; const float* wp; int off, base;
            if (r0 == 0)      { sp = src_cf; dp = dst_cf; wp = ea_cf; off = e0;               base = 0; }
            else if (r0 == 1) { sp = src_fp; dp = dst_fp; wp = ea_fp; off = e0 - E_CF;        base = FP_BASE; }
            else              { sp = src_pp; dp = dst_pp; wp = ea_pp; off = e0 - E_CF - E_FP; base = PP_BASE; }
            int4 s4 = *(const int4*)(sp + off);
            int4 d4 = *(const int4*)(dp + off);
            float4 w4 = *(const float4*)(wp + off);
            s_[0] = s4.x; s_[1] = s4.y; s_[2] = s4.z; s_[3] = s4.w;
            d_[0] = d4.x + base; d_[1] = d4.y + base; d_[2] = d4.z + base; d_[3] = d4.w + base;
            w_[0] = w4.x; w_[1] = w4.y; w_[2] = w4.z; w_[3] = w4.w;
            nv = 4;
        } else {
#pragma unroll
            for (int i = 0; i < 4; ++i) {
                int e = e0 + i;
                if (e < E_CF)                { s_[nv] = src_cf[e]; d_[nv] = dst_cf[e]; w_[nv] = ea_cf[e]; }
                else if (e < E_CF + E_FP)    { int q = e - E_CF; s_[nv] = src_fp[q]; d_[nv] = dst_fp[q] + FP_BASE; w_[nv] = ea_fp[q]; }
                else                         { int q = e - E_CF - E_FP; s_[nv] = src_pp[q]; d_[nv] = dst_pp[q] + PP_BASE; w_[nv] = ea_pp[q]; }
                ++nv;
            }
        }
    } else {
        for (int i = 0; i < 4; ++i) {
            int e = e0 + i;
            if (e >= E_TOT) break;
            if (e < E_CF)                { s_[nv] = src_cf[e]; d_[nv] = dst_cf[e]; w_[nv] = ea_cf[e]; }
            else if (e < E_CF + E_FP)    { int q = e - E_CF; s_[nv] = src_fp[q]; d_[nv] = dst_fp[q] + FP_BASE; w_[nv] = ea_fp[q]; }
            else                         { int q = e - E_CF - E_FP; s_[nv] = src_pp[q]; d_[nv] = dst_pp[q] + PP_BASE; w_[nv] = ea_pp[q]; }
            ++nv;
        }
    }

    for (int i = 0; i < nv; ++i) {
        int d = d_[i];
        atomicAdd(&cnt[d], 1);                    // histogram (result unused -> non-blocking)
        int b = bucket_of(d);
        int t = atomicAdd(&bcnt[b], 1);
        if (t < BINCAP) {
            bbuf[b][t] = make_int2(s_[i], __float_as_int(w_[i]));
            bd[b][t] = d;
        } else {                                  // rare overflow: direct global
            int g = atomicAdd(&scur[b], 1);
            if (g < BCAP) {
                stg_a[(size_t)b * BCAP + g] = make_int2(s_[i], __float_as_int(w_[i]));
                stg_d[(size_t)b * BCAP + g] = d;
            }
        }
    }
    __syncthreads();
    if (threadIdx.x < NBKT) {
        int n = bcnt[threadIdx.x]; if (n > BINCAP) n = BINCAP;
        bcnt[threadIdx.x] = n;
        bbase[threadIdx.x] = (n > 0) ? atomicAdd(&scur[threadIdx.x], n) : 0;
    }
    __syncthreads();
    for (int b = 0; b < NBKT; ++b) {
        int n = bcnt[b];
        int base = bbase[b];
        for (int i = threadIdx.x; i < n; i += 256) {
            int o = base + i;
            if (o < BCAP) {
                stg_a[(size_t)b * BCAP + o] = bbuf[b][i];
                stg_d[(size_t)b * BCAP + o] = bd[b][i];
            }
        }
    }
}

// ======== scans over 800k counts (2048/block) ========
__global__ __launch_bounds__(256) void k_scan1(const int* __restrict__ cnt,
                                               int* __restrict__ bsum) {
    __shared__ int sh[256];
    int base = blockIdx.x * 2048 + threadIdx.x * 8;
    int s = 0;
#pragma unroll
    for (int i = 0; i < 8; ++i) { int idx = base + i; if (idx < NROWS) s += cnt[idx]; }
    sh[threadIdx.x] = s;
    __syncthreads();
    for (int off = 128; off > 0; off >>= 1) {
        if (threadIdx.x < off) sh[threadIdx.x] += sh[threadIdx.x + off];
        __syncthreads();
    }
    if (threadIdx.x == 0) bsum[blockIdx.x] = sh[0];
}

__global__ __launch_bounds__(512) void k_scan2(int* __restrict__ bsum, int nb) {
    __shared__ int sh[512];
    int t = threadIdx.x;
    int v = (t < nb) ? bsum[t] : 0;
    sh[t] = v;
    __syncthreads();
    for (int off = 1; off < 512; off <<= 1) {
        int add = (t >= off) ? sh[t - off] : 0;
        __syncthreads();
        sh[t] += add;
        __syncthreads();
    }
    if (t < nb) bsum[t] = sh[t] - v;
}

__global__ __launch_bounds__(256) void k_scan3(const int* __restrict__ cnt,
                                               const int* __restrict__ bsum,
                                               int* __restrict__ rowptr,
                                               int* __restrict__ cur) {
    __shared__ int sh[256];
    int base = blockIdx.x * 2048 + threadIdx.x * 8;
    int c[8]; int s = 0;
#pragma unroll
    for (int i = 0; i < 8; ++i) { int idx = base + i; c[i] = (idx < NROWS) ? cnt[idx] : 0; s += c[i]; }
    sh[threadIdx.x] = s;
    __syncthreads();
    int v = s;
    for (int off = 1; off < 256; off <<= 1) {
        int add = (threadIdx.x >= off) ? sh[threadIdx.x - off] : 0;
        __syncthreads();
        sh[threadIdx.x] += add;
        __syncthreads();
    }
    int excl = sh[threadIdx.x] - v + bsum[blockIdx.x];
#pragma unroll
    for (int i = 0; i < 8; ++i) {
        int idx = base + i;
        if (idx < NROWS) {
            rowptr[idx] = excl; cur[idx] = excl; excl += c[i];
            if (idx == NROWS - 1) rowptr[NROWS] = excl;
        }
    }
}

// ======== pass 2: bucket-local scatter to exact CSR slots (XCD-pinned) ========
__global__ __launch_bounds__(256) void k_pass2(const int2* __restrict__ stg_a,
                                               const int* __restrict__ stg_d,
                                               const int* __restrict__ scur,
                                               int* __restrict__ cur,
                                               int2* __restrict__ pe) {
    int b = blockIdx.x & 63;                      // b%8 == blockIdx%8 -> XCD-pinned
    int chunk = blockIdx.x >> 6;                  // 0..15
    int n = scur[b]; if (n > BCAP) n = BCAP;
    int per = (n + 15) >> 4;
    int lo = chunk * per;
    int hi = lo + per; if (hi > n) hi = n;
    for (int i = lo + (int)threadIdx.x; i < hi; i += 256) {
        int d = stg_d[(size_t)b * BCAP + i];
        int slot = atomicAdd(&cur[d], 1);
        pe[slot] = stg_a[(size_t)b * BCAP + i];
    }
}

// ======== fused gather(cells->faces) + transform + concat ========
__global__ __launch_bounds__(256) void k_gather8_tf(const float* __restrict__ xc,
                                                    const int* __restrict__ ptr,
                                                    const int2* __restrict__ pe,
                                                    const float* __restrict__ x_face,
                                                    const float* __restrict__ W,
                                                    const float* __restrict__ b,
                                                    unsigned short* __restrict__ yfp) {
    __shared__ float Ws[512];
    __shared__ float bs[64];
    for (int i = threadIdx.x; i < 512; i += 256) Ws[i] = W[i];
    if (threadIdx.x < 64) bs[threadIdx.x] = b[threadIdx.x];
    __syncthreads();
    int r = blockIdx.x * 256 + threadIdx.x;
    if (r >= N_FACES) return;
    int e = ptr[r], end = ptr[r + 1];
    float a[8] = {};
    for (; e + 1 < end; e += 2) {
        int2 q0 = pe[e], q1 = pe[e + 1];
        float w0 = __int_as_float(q0.y), w1 = __int_as_float(q1.y);
        const float* p0 = xc + (size_t)q0.x * 8;
        const float* p1 = xc + (size_t)q1.x * 8;
        float4 u0 = *(const float4*)p0, u1 = *(const float4*)(p0 + 4);
        float4 v0 = *(const float4*)p1, v1 = *(const float4*)(p1 + 4);
        a[0] += w0 * u0.x + w1 * v0.x; a[1] += w0 * u0.y + w1 * v0.y;
        a[2] += w0 * u0.z + w1 * v0.z; a[3] += w0 * u0.w + w1 * v0.w;
        a[4] += w0 * u1.x + w1 * v1.x; a[5] += w0 * u1.y + w1 * v1.y;
        a[6] += w0 * u1.z + w1 * v1.z; a[7] += w0 * u1.w + w1 * v1.w;
    }
    if (e < end) {
        int2 q0 = pe[e];
        float w0 = __int_as_float(q0.y);
        const float* p0 = xc + (size_t)q0.x * 8;
        float4 u0 = *(const float4*)p0, u1 = *(const float4*)(p0 + 4);
        a[0] += w0 * u0.x; a[1] += w0 * u0.y; a[2] += w0 * u0.z; a[3] += w0 * u0.w;
        a[4] += w0 * u1.x; a[5] += w0 * u1.y; a[6] += w0 * u1.z; a[7] += w0 * u1.w;
    }
    unsigned short* orow = yfp + (size_t)r * 96;
#pragma unroll
    for (int c4 = 0; c4 < 4; ++c4) {
        int j0 = c4 * 16;
        float acc[16];
#pragma unroll
        for (int i = 0; i < 16; ++i) acc[i] = bs[j0 + i];
#pragma unroll
        for (int k = 0; k < 8; ++k) {
            float x = a[k];
            const float* wr = Ws + k * 64 + j0;
#pragma unroll
            for (int i = 0; i < 16; ++i) acc[i] += x * wr[i];
        }
        u16x8 o0, o1;
#pragma unroll
        for (int i = 0; i < 8; ++i) { o0[i] = f2bf(acc[i]); o1[i] = f2bf(acc[8 + i]); }
        *(u16x8*)(orow + j0) = o0;
        *(u16x8*)(orow + j0 + 8) = o1;
    }
    float4 xf0 = *(const float4*)(x_face + (size_t)r * 8);
    float4 xf1 = *(const float4*)(x_face + (size_t)r * 8 + 4);
    u16x8 xo;
    xo[0] = f2bf(xf0.x); xo[1] = f2bf(xf0.y); xo[2] = f2bf(xf0.z); xo[3] = f2bf(xf0.w);
    xo[4] = f2bf(xf1.x); xo[5] = f2bf(xf1.y); xo[6] = f2bf(xf1.z); xo[7] = f2bf(xf1.w);
    *(u16x8*)(orow + 64) = xo;
}

// ======== faces->points gather (96 bf16 cols): 2 rows/wave, 4-deep ========
__global__ __launch_bounds__(256) void k_gather96(const unsigned short* __restrict__ feat,
                                                  const int* __restrict__ ptr,
                                                  const int2* __restrict__ pe,
                                                  unsigned short* __restrict__ aggf, int nRows) {
    int gw = (blockIdx.x * 256 + threadIdx.x) >> 6;
    int lane = threadIdx.x & 63;
    int row = gw * 2 + (lane >> 5);
    int l = lane & 31;
    if (row >= nRows) return;
    int e = ptr[row], end = ptr[row + 1];
    float a0 = 0.f, a1 = 0.f, a2 = 0.f;
    for (; e + 3 < end; e += 4) {
        int2 q0 = pe[e], q1 = pe[e + 1], q2 = pe[e + 2], q3 = pe[e + 3];
        float w0 = __int_as_float(q0.y), w1 = __int_as_float(q1.y);
        float w2 = __int_as_float(q2.y), w3 = __int_as_float(q3.y);
        const unsigned short* f0 = feat + (size_t)q0.x * 96 + l;
        const unsigned short* f1 = feat + (size_t)q1.x * 96 + l;
        const unsigned short* f2 = feat + (size_t)q2.x * 96 + l;
        const unsigned short* f3 = feat + (size_t)q3.x * 96 + l;
        a0 += w0 * bf2f(f0[0])  + w1 * bf2f(f1[0])  + w2 * bf2f(f2[0])  + w3 * bf2f(f3[0]);
        a1 += w0 * bf2f(f0[32]) + w1 * bf2f(f1[32]) + w2 * bf2f(f2[32]) + w3 * bf2f(f3[32]);
        a2 += w0 * bf2f(f0[64]) + w1 * bf2f(f1[64]) + w2 * bf2f(f2[64]) + w3 * bf2f(f3[64]);
    }
    for (; e < end; ++e) {
        int2 q0 = pe[e];
        float w0 = __int_as_float(q0.y);
        const unsigned short* f0 = feat + (size_t)q0.x * 96 + l;
        a0 += w0 * bf2f(f0[0]); a1 += w0 * bf2f(f0[32]); a2 += w0 * bf2f(f0[64]);
    }
    unsigned short* o = aggf + (size_t)row * 96 + l;
    o[0] = f2bf(a0); o[32] = f2bf(a1); o[64] = f2bf(a2);
}

// ======== points->points gather (128 bf16 cols): 2 rows/wave, 4-deep ========
__global__ __launch_bounds__(256) void k_gather128pp(const unsigned short* __restrict__ feat,
                                                     const int* __restrict__ ptr,
                                                     const int2* __restrict__ pe,
                                                     unsigned short* __restrict__ aggp, int nRows) {
    int gw = (blockIdx.x * 256 + threadIdx.x) >> 6;
    int lane = threadIdx.x & 63;
    int row = gw * 2 + (lane >> 5);
    int l = lane & 31;
    if (row >= nRows) return;
    int e = ptr[row], end = ptr[row + 1];
    float a0 = 0.f, a1 = 0.f, a2 = 0.f, a3 = 0.f;
    for (; e + 3 < end; e += 4) {
        int2 q0 = pe[e], q1 = pe[e + 1], q2 = pe[e + 2], q3 = pe[e + 3];
        float w0 = __int_as_float(q0.y), w1 = __int_as_float(q1.y);
        float w2 = __int_as_float(q2.y), w3 = __int_as_float(q3.y);
        const unsigned short* f0 = feat + ((size_t)q0.x << 7) + l;
        const unsigned short* f1 = feat + ((size_t)q1.x << 7) + l;
        const unsigned short* f2 = feat + ((size_t)q2.x << 7) + l;
        const unsigned short* f3 = feat + ((size_t)q3.x << 7) + l;
        a0 += w0 * bf2f(f0[0])  + w1 * bf2f(f1[0])  + w2 * bf2f(f2[0])  + w3 * bf2f(f3[0]);
        a1 += w0 * bf2f(f0[32]) + w1 * bf2f(f1[32]) + w2 * bf2f(f2[32]) + w3 * bf2f(f3[32]);
        a2 += w0 * bf2f(f0[64]) + w1 * bf2f(f1[64]) + w2 * bf2f(f2[64]) + w3 * bf2f(f3[64]);
        a3 += w0 * bf2f(f0[96]) + w1 * bf2f(f1[96]) + w2 * bf2f(f2[96]) + w3 * bf2f(f3[96]);
    }
    for (; e < end; ++e) {
        int2 q0 = pe[e];
        float w0 = __int_as_float(q0.y);
        const unsigned short* f0 = feat + ((size_t)q0.x << 7) + l;
        a0 += w0 * bf2f(f0[0]);  a1 += w0 * bf2f(f0[32]);
        a2 += w0 * bf2f(f0[64]); a3 += w0 * bf2f(f0[96]);
    }
    unsigned short* o = aggp + ((size_t)row << 7) + l;
    o[0] = f2bf(a0); o[32] = f2bf(a1); o[64] = f2bf(a2); o[96] = f2bf(a3);
}

// ======== MFMA: y_ptb = bf16(aggf[200k,96] @ W_fp + b_fp) ========
__global__ __launch_bounds__(256) void k_mfma96(const unsigned short* __restrict__ A,
                                                const unsigned short* __restrict__ Bp,
                                                const float* __restrict__ bias,
                                                unsigned short* __restrict__ O) {
    const int w = threadIdx.x >> 6;
    const int lane = threadIdx.x & 63;
    const int rg = w >> 1, cg = w & 1;
    const int row0 = blockIdx.x * 32 + rg * 16;
    bf16x8 bfr[3][4];
#pragma unroll
    for (int ks = 0; ks < 3; ++ks)
#pragma unroll
        for (int c = 0; c < 4; ++c) {
            int ct = cg * 4 + c;
            bfr[ks][c] = *(const bf16x8*)(Bp + ((size_t)(ks * 8 + ct) * 64 + lane) * 8);
        }
    f32x4 acc[4] = {};
    const unsigned short* arow = A + (size_t)(row0 + (lane & 15)) * 96 + ((lane >> 4) * 8);
#pragma unroll
    for (int ks = 0; ks < 3; ++ks) {
        bf16x8 af = *(const bf16x8*)(arow + ks * 32);
#pragma unroll
        for (int c = 0; c < 4; ++c)
            acc[c] = __builtin_amdgcn_mfma_f32_16x16x32_bf16(af, bfr[ks][c], acc[c], 0, 0, 0);
    }
    const int rbase = row0 + (lane >> 4) * 4;
#pragma unroll
    for (int c = 0; c < 4; ++c) {
        int gcol = cg * 64 + c * 16 + (lane & 15);
        float bv = bias[gcol];
#pragma unroll
        for (int r = 0; r < 4; ++r)
            O[(size_t)(rbase + r) * 128 + gcol] = f2bf(acc[c][r] + bv);
    }
}

// ======== MFMA: out = [y_ptb | aggp] @ [W_rt;W_pp] + b_pp ========
__global__ __launch_bounds__(256) void k_mfma_fin(const unsigned short* __restrict__ A1,
                                                  const unsigned short* __restrict__ A2,
                                                  const unsigned short* __restrict__ Bp,
                                                  const float* __restrict__ bias,
                                                  float* __restrict__ out) {
    const int w = threadIdx.x >> 6;
    const int lane = threadIdx.x & 63;
    const int rg = w >> 1, cg = w & 1;
    const int row0 = blockIdx.x * 32 + rg * 16;
    bf16x8 bfr[8][4];
#pragma unroll
    for (int ks = 0; ks < 8; ++ks)
#pragma unroll
        for (int c = 0; c < 4; ++c) {
            int ct = cg * 4 + c;
            bfr[ks][c] = *(const bf16x8*)(Bp + ((size_t)(ks * 8 + ct) * 64 + lane) * 8);
        }
    f32x4 acc[4] = {};
    const unsigned short* a1 = A1 + (size_t)(row0 + (lane & 15)) * 128 + ((lane >> 4) * 8);
    const unsigned short* a2 = A2 + (size_t)(row0 + (lane & 15)) * 128 + ((lane >> 4) * 8);
#pragma unroll
    for (int ks = 0; ks < 4; ++ks) {
        bf16x8 af = *(const bf16x8*)(a1 + ks * 32);
#pragma unroll
        for (int c = 0; c < 4; ++c)
            acc[c] = __builtin_amdgcn_mfma_f32_16x16x32_bf16(af, bfr[ks][c], acc[c], 0, 0, 0);
    }
#pragma unroll
    for (int ks = 0; ks < 4; ++ks) {
        bf16x8 af = *(const bf16x8*)(a2 + ks * 32);
#pragma unroll
        for (int c = 0; c < 4; ++c)
            acc[c] = __builtin_amdgcn_mfma_f32_16x16x32_bf16(af, bfr[ks + 4][c], acc[c], 0, 0, 0);
    }
    const int rbase = row0 + (lane >> 4) * 4;
#pragma unroll
    for (int c = 0; c < 4; ++c) {
        int gcol = cg * 64 + c * 16 + (lane & 15);
        float bv = bias[gcol];
#pragma unroll
        for (int r = 0; r < 4; ++r)
            out[(size_t)(rbase + r) * 128 + gcol] = acc[c][r] + bv;
    }
}

extern "C" void kernel_launch(void* const* d_in, const int* in_sizes, int n_in,
                              void* d_out, int out_size, void* d_ws, size_t ws_size,
                              hipStream_t stream) {
    const float* x_centers = (const float*)d_in[0];
    const float* x_face    = (const float*)d_in[1];
    const float* W_cf      = (const float*)d_in[2];
    const float* b_cf      = (const float*)d_in[3];
    const float* W_fp      = (const float*)d_in[4];
    const float* b_fp      = (const float*)d_in[5];
    const float* W_pp      = (const float*)d_in[6];
    const float* W_rt      = (const float*)d_in[7];
    const float* b_pp      = (const float*)d_in[8];
    const float* ea_cf     = (const float*)d_in[9];
    const float* ea_fp     = (const float*)d_in[10];
    const float* ea_pp     = (const float*)d_in[11];
    const int* src_cf      = (const int*)d_in[12];
    const int* dst_cf      = (const int*)d_in[13];
    const int* src_fp      = (const int*)d_in[14];
    const int* dst_fp      = (const int*)d_in[15];
    const int* src_pp      = (const int*)d_in[16];
    const int* dst_pp      = (const int*)d_in[17];
    float* out = (float*)d_out;

    char* ws = (char*)d_ws;
    unsigned short* yfp    = (unsigned short*)(ws + 0);           // bf16 [400k][96]  76.8MB
    unsigned short* aggf   = (unsigned short*)(ws + 80000000);    // bf16 [200k][96]  38.4MB
    unsigned short* y_ptb  = (unsigned short*)(ws + 120000000);   // bf16 [200k][128] 51.2MB
    unsigned short* aggp   = (unsigned short*)(ws + 172000000);   // bf16 [200k][128] 51.2MB
    int2* pe_all           = (int2*)(ws + 224000000);             // 2.8M recs 22.4MB
    int*  cnt_all          = (int*)(ws + 247000000);              // 800000 counts -> cursors
    int*  ptr_all          = (int*)(ws + 251000000);              // 800001 rowptr
    int*  bsum             = (int*)(ws + 255000000);              // 391
    unsigned short* Bp_fp  = (unsigned short*)(ws + 255100000);   // 24KB
    unsigned short* Bp_fin = (unsigned short*)(ws + 255200000);   // 64KB
    int2* stg_a            = (int2*)(ws + 256000000);             // 64*65536*8B = 33.6MB
    int*  stg_d            = (int*)(ws + 290000000);              // 64*65536*4B = 16.8MB
    int*  scur             = (int*)(ws + 307000000);              // 64 bucket cursors

    // CSR build: zero+pack -> pass1 (bin + hist) -> scans -> pass2 (bucket-local scatter)
    k_pre<<<3302, 256, 0, stream>>>(cnt_all, scur, W_fp, W_rt, W_pp, Bp_fp, Bp_fin);
    k_pass1<<<2735, 256, 0, stream>>>(src_cf, dst_cf, ea_cf, src_fp, dst_fp, ea_fp,
                                      src_pp, dst_pp, ea_pp, cnt_all, scur, stg_a, stg_d);
    k_scan1<<<391, 256, 0, stream>>>(cnt_all, bsum);
    k_scan2<<<1, 512, 0, stream>>>(bsum, 391);
    k_scan3<<<391, 256, 0, stream>>>(cnt_all, bsum, ptr_all, cnt_all);
    k_pass2<<<NBKT * 16, 256, 0, stream>>>(stg_a, stg_d, scur, cnt_all, pe_all);
    // pipeline
    k_gather8_tf<<<1563, 256, 0, stream>>>(x_centers, ptr_all, pe_all, x_face, W_cf, b_cf, yfp);
    k_gather96<<<25000, 256, 0, stream>>>(yfp, ptr_all + FP_BASE, pe_all, aggf, N_POINTS);
    k_mfma96<<<6250, 256, 0, stream>>>(aggf, Bp_fp, b_fp, y_ptb);
    k_gather128pp<<<25000, 256, 0, stream>>>(y_ptb, ptr_all + PP_BASE, pe_all, aggp, N_POINTS);
    k_mfma_fin<<<6250, 256, 0, stream>>>(y_ptb, aggp, Bp_fin, b_pp, out);
}

// Round 12
// 420.838 us; speedup vs baseline: 2.7948x; 1.4289x over previous
//
#include <hip/hip_runtime.h>
#include <hip/hip_bf16.h>

#define N_CELLS  200000
#define N_FACES  400000
#define N_POINTS 200000
#define E_CF     800000
#define E_FP     800000
#define E_PP     1200000
#define CAP_CF   16
#define CAP_FP   24
#define CAP_PP   32
#define OVF_CAP  4096

typedef __attribute__((ext_vector_type(8))) short bf16x8;
typedef __attribute__((ext_vector_type(8))) unsigned short u16x8;
typedef __attribute__((ext_vector_type(4))) float f32x4;

__device__ __forceinline__ float bf2f(unsigned short u) {
    union { unsigned int i; float f; } v; v.i = ((unsigned int)u) << 16; return v.f;
}
__device__ __forceinline__ unsigned short f2bf(float f) {
    __hip_bfloat16 h = __float2bfloat16(f);
    return *reinterpret_cast<unsigned short*>(&h);
}

// ======== fused: zero cnt (800k ints) + zero ovf counters + weight packs ========
__global__ __launch_bounds__(256) void k_pre(int* __restrict__ cnt,
                                             int* __restrict__ ovfn,
                                             const float* __restrict__ W_fp,
                                             const float* __restrict__ W_rt,
                                             const float* __restrict__ W_pp,
                                             unsigned short* __restrict__ Bp_fp,
                                             unsigned short* __restrict__ Bp_fin) {
    int b = blockIdx.x;
    if (b < 782) {
        int t = b * 256 + threadIdx.x;
        if (t < 200000) ((int4*)cnt)[t] = make_int4(0, 0, 0, 0);
    } else if (b == 782) {
        if (threadIdx.x < 3) ovfn[threadIdx.x] = 0;
    } else if (b < 831) {                         // pack W_fp: 48 blocks
        int t = (b - 783) * 256 + threadIdx.x;    // 12288
        int j = t & 7, lane = (t >> 3) & 63, ct = (t >> 9) & 7, ks = t >> 12;
        int k = ks * 32 + ((lane >> 4) & 3) * 8 + j;
        int col = ct * 16 + (lane & 15);
        Bp_fp[t] = f2bf(W_fp[k * 128 + col]);
    } else {                                      // pack fin: 128 blocks
        int t = (b - 831) * 256 + threadIdx.x;    // 32768
        int j = t & 7, lane = (t >> 3) & 63, ct = (t >> 9) & 7, ks = t >> 12;
        int k = ks * 32 + ((lane >> 4) & 3) * 8 + j;   // 0..255
        int col = ct * 16 + (lane & 15);
        float v = (k < 128) ? W_rt[k * 128 + col] : W_pp[(k - 128) * 128 + col];
        Bp_fin[t] = f2bf(v);
    }
}

// ======== fixed-stride fill (partitioned sweep for locality) ========
__device__ __forceinline__ void fill_fixed(const int* __restrict__ src,
                                           const int* __restrict__ dst,
                                           const float* __restrict__ ea,
                                           int nE, int rlo, int rhi, int cap,
                                           int tid0, int stride,
                                           int* __restrict__ cnt,
                                           int2* __restrict__ pe,
                                           int* __restrict__ ovfn,
                                           int4* __restrict__ ovf) {
    for (int e = tid0; e < nE; e += stride) {
        int4 d4 = *(const int4*)(dst + e);
        int4 s4 = *(const int4*)(src + e);
        float4 w4 = *(const float4*)(ea + e);
        int dd[4] = {d4.x, d4.y, d4.z, d4.w};
        int ss[4] = {s4.x, s4.y, s4.z, s4.w};
        float ww[4] = {w4.x, w4.y, w4.z, w4.w};
#pragma unroll
        for (int i = 0; i < 4; ++i) {
            int d = dd[i];
            if (d >= rlo && d < rhi) {
                int t = atomicAdd(&cnt[d], 1);
                if (t < cap)
                    pe[(size_t)d * cap + t] = make_int2(ss[i], __float_as_int(ww[i]));
                else {
                    int g = atomicAdd(ovfn, 1);
                    if (g < OVF_CAP) ovf[g] = make_int4(d, ss[i], __float_as_int(ww[i]), 0);
                }
            }
        }
    }
}

__global__ __launch_bounds__(256) void k_fill_cf(const int* __restrict__ src_cf,
                                                 const int* __restrict__ dst_cf,
                                                 const float* __restrict__ ea_cf,
                                                 int* __restrict__ cnt_cf,
                                                 int2* __restrict__ pe_cf,
                                                 int* __restrict__ ovfn,
                                                 int4* __restrict__ ovf) {
    int p = blockIdx.x & 7;                       // partition -> XCD (perf-only)
    int blk = blockIdx.x >> 3;                    // 0..127
    int rlo = p * 50000, rhi = rlo + 50000;
    int tid0 = (blk * 256 + (int)threadIdx.x) * 4;
    fill_fixed(src_cf, dst_cf, ea_cf, E_CF, rlo, rhi, CAP_CF,
               tid0, 128 * 256 * 4, cnt_cf, pe_cf, ovfn, ovf);
}

// ======== MEGA: fill_fp ∥ fill_pp ∥ gather8_tf ========
__global__ __launch_bounds__(256) void k_mega(const int* __restrict__ src_fp,
                                              const int* __restrict__ dst_fp,
                                              const float* __restrict__ ea_fp,
                                              const int* __restrict__ src_pp,
                                              const int* __restrict__ dst_pp,
                                              const float* __restrict__ ea_pp,
                                              int* __restrict__ cnt_fp,
                                              int2* __restrict__ pe_fp,
                                              int* __restrict__ cnt_pp,
                                              int2* __restrict__ pe_pp,
                                              int* __restrict__ ovfn,
                                              int4* __restrict__ ovf_fp,
                                              int4* __restrict__ ovf_pp,
                                              const float* __restrict__ xc,
                                              const int* __restrict__ cnt_cf,
                                              const int2* __restrict__ pe_cf,
                                              const int* __restrict__ ovfn_cf,
                                              const int4* __restrict__ ovf_cf,
                                              const float* __restrict__ x_face,
                                              const float* __restrict__ W,
                                              const float* __restrict__ bvec,
                                              unsigned short* __restrict__ yfp) {
    __shared__ float Ws[512];
    __shared__ float bs[64];
    int b = blockIdx.x;
    if (b < 1024) {                               // ---- fill fp ----
        int p = b & 7;
        int blk = b >> 3;
        int rlo = p * 25000, rhi = rlo + 25000;
        int tid0 = (blk * 256 + (int)threadIdx.x) * 4;
        fill_fixed(src_fp, dst_fp, ea_fp, E_FP, rlo, rhi, CAP_FP,
                   tid0, 128 * 256 * 4, cnt_fp, pe_fp, ovfn + 1, ovf_fp);
        return;
    }
    if (b < 2048) {                               // ---- fill pp ----
        int p = b & 7;
        int blk = (b - 1024) >> 3;
        int rlo = p * 25000, rhi = rlo + 25000;
        int tid0 = (blk * 256 + (int)threadIdx.x) * 4;
        fill_fixed(src_pp, dst_pp, ea_pp, E_PP, rlo, rhi, CAP_PP,
                   tid0, 128 * 256 * 4, cnt_pp, pe_pp, ovfn + 2, ovf_pp);
        return;
    }
    // ---- gather8_tf: one thread per face row ----
    for (int i = threadIdx.x; i < 512; i += 256) Ws[i] = W[i];
    if (threadIdx.x < 64) bs[threadIdx.x] = bvec[threadIdx.x];
    __syncthreads();
    int r = (b - 2048) * 256 + threadIdx.x;
    if (r >= N_FACES) return;
    int n = cnt_cf[r]; if (n > CAP_CF) n = CAP_CF;
    const int2* prow = pe_cf + (size_t)r * CAP_CF;
    float a[8] = {};
    int e = 0;
    for (; e + 1 < n; e += 2) {
        int2 q0 = prow[e], q1 = prow[e + 1];
        float w0 = __int_as_float(q0.y), w1 = __int_as_float(q1.y);
        const float* p0 = xc + (size_t)q0.x * 8;
        const float* p1 = xc + (size_t)q1.x * 8;
        float4 u0 = *(const float4*)p0, u1 = *(const float4*)(p0 + 4);
        float4 v0 = *(const float4*)p1, v1 = *(const float4*)(p1 + 4);
        a[0] += w0 * u0.x + w1 * v0.x; a[1] += w0 * u0.y + w1 * v0.y;
        a[2] += w0 * u0.z + w1 * v0.z; a[3] += w0 * u0.w + w1 * v0.w;
        a[4] += w0 * u1.x + w1 * v1.x; a[5] += w0 * u1.y + w1 * v1.y;
        a[6] += w0 * u1.z + w1 * v1.z; a[7] += w0 * u1.w + w1 * v1.w;
    }
    if (e < n) {
        int2 q0 = prow[e];
        float w0 = __int_as_float(q0.y);
        const float* p0 = xc + (size_t)q0.x * 8;
        float4 u0 = *(const float4*)p0, u1 = *(const float4*)(p0 + 4);
        a[0] += w0 * u0.x; a[1] += w0 * u0.y; a[2] += w0 * u0.z; a[3] += w0 * u0.w;
        a[4] += w0 * u1.x; a[5] += w0 * u1.y; a[6] += w0 * u1.z; a[7] += w0 * u1.w;
    }
    int no = *ovfn_cf;                            // 0 in practice
    if (no > 0) {
        if (no > OVF_CAP) no = OVF_CAP;
        for (int i = 0; i < no; ++i) {
            int4 o = ovf_cf[i];
            if (o.x == r) {
                float w0 = __int_as_float(o.z);
                const float* p0 = xc + (size_t)o.y * 8;
#pragma unroll
                for (int k = 0; k < 8; ++k) a[k] += w0 * p0[k];
            }
        }
    }
    unsigned short* orow = yfp + (size_t)r * 96;
#pragma unroll
    for (int c4 = 0; c4 < 4; ++c4) {
        int j0 = c4 * 16;
        float acc[16];
#pragma unroll
        for (int i = 0; i < 16; ++i) acc[i] = bs[j0 + i];
#pragma unroll
        for (int k = 0; k < 8; ++k) {
            float x = a[k];
            const float* wr = Ws + k * 64 + j0;
#pragma unroll
            for (int i = 0; i < 16; ++i) acc[i] += x * wr[i];
        }
        u16x8 o0, o1;
#pragma unroll
        for (int i = 0; i < 8; ++i) { o0[i] = f2bf(acc[i]); o1[i] = f2bf(acc[8 + i]); }
        *(u16x8*)(orow + j0) = o0;
        *(u16x8*)(orow + j0 + 8) = o1;
    }
    float4 xf0 = *(const float4*)(x_face + (size_t)r * 8);
    float4 xf1 = *(const float4*)(x_face + (size_t)r * 8 + 4);
    u16x8 xo;
    xo[0] = f2bf(xf0.x); xo[1] = f2bf(xf0.y); xo[2] = f2bf(xf0.z); xo[3] = f2bf(xf0.w);
    xo[4] = f2bf(xf1.x); xo[5] = f2bf(xf1.y); xo[6] = f2bf(xf1.z); xo[7] = f2bf(xf1.w);
    *(u16x8*)(orow + 64) = xo;
}

// ======== faces->points gather (96 bf16 cols): 2 rows/wave, 4-deep ========
__global__ __launch_bounds__(256) void k_gather96(const unsigned short* __restrict__ feat,
                                                  const int* __restrict__ cnt,
                                                  const int2* __restrict__ pe,
                                                  const int* __restrict__ ovfn,
                                                  const int4* __restrict__ ovf,
                                                  unsigned short* __restrict__ aggf, int nRows) {
    int gw = (blockIdx.x * 256 + threadIdx.x) >> 6;
    int lane = threadIdx.x & 63;
    int row = gw * 2 + (lane >> 5);
    int l = lane & 31;
    if (row >= nRows) return;
    int n = cnt[row]; if (n > CAP_FP) n = CAP_FP;
    const int2* prow = pe + (size_t)row * CAP_FP;
    float a0 = 0.f, a1 = 0.f, a2 = 0.f;
    int e = 0;
    for (; e + 3 < n; e += 4) {
        int2 q0 = prow[e], q1 = prow[e + 1], q2 = prow[e + 2], q3 = prow[e + 3];
        float w0 = __int_as_float(q0.y), w1 = __int_as_float(q1.y);
        float w2 = __int_as_float(q2.y), w3 = __int_as_float(q3.y);
        const unsigned short* f0 = feat + (size_t)q0.x * 96 + l;
        const unsigned short* f1 = feat + (size_t)q1.x * 96 + l;
        const unsigned short* f2 = feat + (size_t)q2.x * 96 + l;
        const unsigned short* f3 = feat + (size_t)q3.x * 96 + l;
        a0 += w0 * bf2f(f0[0])  + w1 * bf2f(f1[0])  + w2 * bf2f(f2[0])  + w3 * bf2f(f3[0]);
        a1 += w0 * bf2f(f0[32]) + w1 * bf2f(f1[32]) + w2 * bf2f(f2[32]) + w3 * bf2f(f3[32]);
        a2 += w0 * bf2f(f0[64]) + w1 * bf2f(f1[64]) + w2 * bf2f(f2[64]) + w3 * bf2f(f3[64]);
    }
    for (; e < n; ++e) {
        int2 q0 = prow[e];
        float w0 = __int_as_float(q0.y);
        const unsigned short* f0 = feat + (size_t)q0.x * 96 + l;
        a0 += w0 * bf2f(f0[0]); a1 += w0 * bf2f(f0[32]); a2 += w0 * bf2f(f0[64]);
    }
    int no = *ovfn;
    if (no > 0) {
        if (no > OVF_CAP) no = OVF_CAP;
        for (int i = 0; i < no; ++i) {
            int4 o = ovf[i];
            if (o.x == row) {
                float w0 = __int_as_float(o.z);
                const unsigned short* f0 = feat + (size_t)o.y * 96 + l;
                a0 += w0 * bf2f(f0[0]); a1 += w0 * bf2f(f0[32]); a2 += w0 * bf2f(f0[64]);
            }
        }
    }
    unsigned short* o = aggf + (size_t)row * 96 + l;
    o[0] = f2bf(a0); o[32] = f2bf(a1); o[64] = f2bf(a2);
}

// ======== points->points gather (128 bf16 cols): 2 rows/wave, 4-deep ========
__global__ __launch_bounds__(256) void k_gather128pp(const unsigned short* __restrict__ feat,
                                                     const int* __restrict__ cnt,
                                                     const int2* __restrict__ pe,
                                                     const int* __restrict__ ovfn,
                                                     const int4* __restrict__ ovf,
                                                     unsigned short* __restrict__ aggp, int nRows) {
    int gw = (blockIdx.x * 256 + threadIdx.x) >> 6;
    int lane = threadIdx.x & 63;
    int row = gw * 2 + (lane >> 5);
    int l = lane & 31;
    if (row >= nRows) return;
    int n = cnt[row]; if (n > CAP_PP) n = CAP_PP;
    const int2* prow = pe + (size_t)row * CAP_PP;
    float a0 = 0.f, a1 = 0.f, a2 = 0.f, a3 = 0.f;
    int e = 0;
    for (; e + 3 < n; e += 4) {
        int2 q0 = prow[e], q1 = prow[e + 1], q2 = prow[e + 2], q3 = prow[e + 3];
        float w0 = __int_as_float(q0.y), w1 = __int_as_float(q1.y);
        float w2 = __int_as_float(q2.y), w3 = __int_as_float(q3.y);
        const unsigned short* f0 = feat + ((size_t)q0.x << 7) + l;
        const unsigned short* f1 = feat + ((size_t)q1.x << 7) + l;
        const unsigned short* f2 = feat + ((size_t)q2.x << 7) + l;
        const unsigned short* f3 = feat + ((size_t)q3.x << 7) + l;
        a0 += w0 * bf2f(f0[0])  + w1 * bf2f(f1[0])  + w2 * bf2f(f2[0])  + w3 * bf2f(f3[0]);
        a1 += w0 * bf2f(f0[32]) + w1 * bf2f(f1[32]) + w2 * bf2f(f2[32]) + w3 * bf2f(f3[32]);
        a2 += w0 * bf2f(f0[64]) + w1 * bf2f(f1[64]) + w2 * bf2f(f2[64]) + w3 * bf2f(f3[64]);
        a3 += w0 * bf2f(f0[96]) + w1 * bf2f(f1[96]) + w2 * bf2f(f2[96]) + w3 * bf2f(f3[96]);
    }
    for (; e < n; ++e) {
        int2 q0 = prow[e];
        float w0 = __int_as_float(q0.y);
        const unsigned short* f0 = feat + ((size_t)q0.x << 7) + l;
        a0 += w0 * bf2f(f0[0]);  a1 += w0 * bf2f(f0[32]);
        a2 += w0 * bf2f(f0[64]); a3 += w0 * bf2f(f0[96]);
    }
    int no = *ovfn;
    if (no > 0) {
        if (no > OVF_CAP) no = OVF_CAP;
        for (int i = 0; i < no; ++i) {
            int4 o = ovf[i];
            if (o.x == row) {
                float w0 = __int_as_float(o.z);
                const unsigned short* f0 = feat + ((size_t)o.y << 7) + l;
                a0 += w0 * bf2f(f0[0]);  a1 += w0 * bf2f(f0[32]);
                a2 += w0 * bf2f(f0[64]); a3 += w0 * bf2f(f0[96]);
            }
        }
    }
    unsigned short* o = aggp + ((size_t)row << 7) + l;
    o[0] = f2bf(a0); o[32] = f2bf(a1); o[64] = f2bf(a2); o[96] = f2bf(a3);
}

// ======== MFMA: y_ptb = bf16(aggf[200k,96] @ W_fp + b_fp) ========
__global__ __launch_bounds__(256) void k_mfma96(const unsigned short* __restrict__ A,
                                                const unsigned short* __restrict__ Bp,
                                                const float* __restrict__ bias,
                                                unsigned short* __restrict__ O) {
    const int w = threadIdx.x >> 6;
    const int lane = threadIdx.x & 63;
    const int rg = w >> 1, cg = w & 1;
    const int row0 = blockIdx.x * 32 + rg * 16;
    bf16x8 bfr[3][4];
#pragma unroll
    for (int ks = 0; ks < 3; ++ks)
#pragma unroll
        for (int c = 0; c < 4; ++c) {
            int ct = cg * 4 + c;
            bfr[ks][c] = *(const bf16x8*)(Bp + ((size_t)(ks * 8 + ct) * 64 + lane) * 8);
        }
    f32x4 acc[4] = {};
    const unsigned short* arow = A + (size_t)(row0 + (lane & 15)) * 96 + ((lane >> 4) * 8);
#pragma unroll
    for (int ks = 0; ks < 3; ++ks) {
        bf16x8 af = *(const bf16x8*)(arow + ks * 32);
#pragma unroll
        for (int c = 0; c < 4; ++c)
            acc[c] = __builtin_amdgcn_mfma_f32_16x16x32_bf16(af, bfr[ks][c], acc[c], 0, 0, 0);
    }
    const int rbase = row0 + (lane >> 4) * 4;
#pragma unroll
    for (int c = 0; c < 4; ++c) {
        int gcol = cg * 64 + c * 16 + (lane & 15);
        float bv = bias[gcol];
#pragma unroll
        for (int r = 0; r < 4; ++r)
            O[(size_t)(rbase + r) * 128 + gcol] = f2bf(acc[c][r] + bv);
    }
}

// ======== MFMA: out = [y_ptb | aggp] @ [W_rt;W_pp] + b_pp ========
__global__ __launch_bounds__(256) void k_mfma_fin(const unsigned short* __restrict__ A1,
                                                  const unsigned short* __restrict__ A2,
                                                  const unsigned short* __restrict__ Bp,
                                                  const float* __restrict__ bias,
                                                  float* __restrict__ out) {
    const int w = threadIdx.x >> 6;
    const int lane = threadIdx.x & 63;
    const int rg = w >> 1, cg = w & 1;
    const int row0 = blockIdx.x * 32 + rg * 16;
    bf16x8 bfr[8][4];
#pragma unroll
    for (int ks = 0; ks < 8; ++ks)
#pragma unroll
        for (int c = 0; c < 4; ++c) {
            int ct = cg * 4 + c;
            bfr[ks][c] = *(const bf16x8*)(Bp + ((size_t)(ks * 8 + ct) * 64 + lane) * 8);
        }
    f32x4 acc[4] = {};
    const unsigned short* a1 = A1 + (size_t)(row0 + (lane & 15)) * 128 + ((lane >> 4) * 8);
    const unsigned short* a2 = A2 + (size_t)(row0 + (lane & 15)) * 128 + ((lane >> 4) * 8);
#pragma unroll
    for (int ks = 0; ks < 4; ++ks) {
        bf16x8 af = *(const bf16x8*)(a1 + ks * 32);
#pragma unroll
        for (int c = 0; c < 4; ++c)
            acc[c] = __builtin_amdgcn_mfma_f32_16x16x32_bf16(af, bfr[ks][c], acc[c], 0, 0, 0);
    }
#pragma unroll
    for (int ks = 0; ks < 4; ++ks) {
        bf16x8 af = *(const bf16x8*)(a2 + ks * 32);
#pragma unroll
        for (int c = 0; c < 4; ++c)
            acc[c] = __builtin_amdgcn_mfma_f32_16x16x32_bf16(af, bfr[ks + 4][c], acc[c], 0, 0, 0);
    }
    const int rbase = row0 + (lane >> 4) * 4;
#pragma unroll
    for (int c = 0; c < 4; ++c) {
        int gcol = cg * 64 + c * 16 + (lane & 15);
        float bv = bias[gcol];
#pragma unroll
        for (int r = 0; r < 4; ++r)
            out[(size_t)(rbase + r) * 128 + gcol] = acc[c][r] + bv;
    }
}

extern "C" void kernel_launch(void* const* d_in, const int* in_sizes, int n_in,
                              void* d_out, int out_size, void* d_ws, size_t ws_size,
                              hipStream_t stream) {
    const float* x_centers = (const float*)d_in[0];
    const float* x_face    = (const float*)d_in[1];
    const float* W_cf      = (const float*)d_in[2];
    const float* b_cf      = (const float*)d_in[3];
    const float* W_fp      = (const float*)d_in[4];
    const float* b_fp      = (const float*)d_in[5];
    const float* W_pp      = (const float*)d_in[6];
    const float* W_rt      = (const float*)d_in[7];
    const float* b_pp      = (const float*)d_in[8];
    const float* ea_cf     = (const float*)d_in[9];
    const float* ea_fp     = (const float*)d_in[10];
    const float* ea_pp     = (const float*)d_in[11];
    const int* src_cf      = (const int*)d_in[12];
    const int* dst_cf      = (const int*)d_in[13];
    const int* src_fp      = (const int*)d_in[14];
    const int* dst_fp      = (const int*)d_in[15];
    const int* src_pp      = (const int*)d_in[16];
    const int* dst_pp      = (const int*)d_in[17];
    float* out = (float*)d_out;

    char* ws = (char*)d_ws;
    unsigned short* yfp    = (unsigned short*)(ws + 0);           // bf16 [400k][96]  76.8MB
    unsigned short* y_ptb  = (unsigned short*)(ws + 80000000);    // bf16 [200k][128] 51.2MB
    int2* pe_fp            = (int2*)(ws + 80000000);              // 38.4MB (dead before y_ptb write)
    unsigned short* aggp   = (unsigned short*)(ws + 132000000);   // bf16 [200k][128] 51.2MB
    int2* pe_cf            = (int2*)(ws + 132000000);             // 51.2MB (dead before aggp write)
    unsigned short* aggf   = (unsigned short*)(ws + 184000000);   // bf16 [200k][96]  38.4MB
    int2* pe_pp            = (int2*)(ws + 223000000);             // 51.2MB
    int*  cnt_cf           = (int*)(ws + 275000000);              // 400k
    int*  cnt_fp           = (int*)(ws + 276600000);              // 200k
    int*  cnt_pp           = (int*)(ws + 277400000);              // 200k (cnt block contiguous 3.2MB)
    int4* ovf_cf           = (int4*)(ws + 278300000);             // 64KB
    int4* ovf_fp           = (int4*)(ws + 278400000);
    int4* ovf_pp           = (int4*)(ws + 278500000);
    int*  ovfn             = (int*)(ws + 278600000);              // 3 counters
    unsigned short* Bp_fp  = (unsigned short*)(ws + 278700000);   // 24KB
    unsigned short* Bp_fin = (unsigned short*)(ws + 278800000);   // 64KB

    // zero counters + pack weights
    k_pre<<<959, 256, 0, stream>>>(cnt_cf, ovfn, W_fp, W_rt, W_pp, Bp_fp, Bp_fin);
    // fill cf (partitioned, fixed-stride)
    k_fill_cf<<<1024, 256, 0, stream>>>(src_cf, dst_cf, ea_cf, cnt_cf, pe_cf, ovfn, ovf_cf);
    // MEGA: fill fp + fill pp + gather8_tf
    k_mega<<<2048 + 1563, 256, 0, stream>>>(src_fp, dst_fp, ea_fp, src_pp, dst_pp, ea_pp,
                                            cnt_fp, pe_fp, cnt_pp, pe_pp, ovfn, ovf_fp, ovf_pp,
                                            x_centers, cnt_cf, pe_cf, ovfn, ovf_cf,
                                            x_face, W_cf, b_cf, yfp);
    // faces -> points
    k_gather96<<<25000, 256, 0, stream>>>(yfp, cnt_fp, pe_fp, ovfn + 1, ovf_fp, aggf, N_POINTS);
    k_mfma96<<<6250, 256, 0, stream>>>(aggf, Bp_fp, b_fp, y_ptb);
    // points -> points
    k_gather128pp<<<25000, 256, 0, stream>>>(y_ptb, cnt_pp, pe_pp, ovfn + 2, ovf_pp, aggp, N_POINTS);
    k_mfma_fin<<<6250, 256, 0, stream>>>(y_ptb, aggp, Bp_fin, b_pp, out);
}

// Round 13
// 398.324 us; speedup vs baseline: 2.9528x; 1.0565x over previous
//
#include <hip/hip_runtime.h>
#include <hip/hip_bf16.h>

#define N_CELLS  200000
#define N_FACES  400000
#define N_POINTS 200000
#define E_CF     800000
#define E_FP     800000
#define E_PP     1200000
#define CAP_CF   16
#define CAP_FP   24
#define CAP_PP   32
#define OVF_CAP  4096
#define LDA96    104      // LDS stride (elems): 16B-aligned rows, ~2-way banks
#define LDA128   136

typedef __attribute__((ext_vector_type(8))) short bf16x8;
typedef __attribute__((ext_vector_type(8))) unsigned short u16x8;
typedef __attribute__((ext_vector_type(4))) float f32x4;

__device__ __forceinline__ float bf2f(unsigned short u) {
    union { unsigned int i; float f; } v; v.i = ((unsigned int)u) << 16; return v.f;
}
__device__ __forceinline__ unsigned short f2bf(float f) {
    __hip_bfloat16 h = __float2bfloat16(f);
    return *reinterpret_cast<unsigned short*>(&h);
}

// ======== fixed-stride fill helper (partitioned sweep) ========
__device__ __forceinline__ void fill_fixed(const int* __restrict__ src,
                                           const int* __restrict__ dst,
                                           const float* __restrict__ ea,
                                           int nE, int rlo, int rhi, int cap,
                                           int tid0, int stride,
                                           int* __restrict__ cnt,
                                           int2* __restrict__ pe,
                                           int* __restrict__ ovfn,
                                           int4* __restrict__ ovf) {
    for (int e = tid0; e < nE; e += stride) {
        int4 d4 = *(const int4*)(dst + e);
        int4 s4 = *(const int4*)(src + e);
        float4 w4 = *(const float4*)(ea + e);
        int dd[4] = {d4.x, d4.y, d4.z, d4.w};
        int ss[4] = {s4.x, s4.y, s4.z, s4.w};
        float ww[4] = {w4.x, w4.y, w4.z, w4.w};
#pragma unroll
        for (int i = 0; i < 4; ++i) {
            int d = dd[i];
            if (d >= rlo && d < rhi) {
                int t = atomicAdd(&cnt[d], 1);
                if (t < cap)
                    pe[(size_t)d * cap + t] = make_int2(ss[i], __float_as_int(ww[i]));
                else {
                    int g = atomicAdd(ovfn, 1);
                    if (g < OVF_CAP) ovf[g] = make_int4(d, ss[i], __float_as_int(ww[i]), 0);
                }
            }
        }
    }
}

// ======== fill cf (4 partitions) + weight packs ========
__global__ __launch_bounds__(256) void k_fillcf_pack(const int* __restrict__ src_cf,
                                                     const int* __restrict__ dst_cf,
                                                     const float* __restrict__ ea_cf,
                                                     int* __restrict__ cnt_cf,
                                                     int2* __restrict__ pe_cf,
                                                     int* __restrict__ ovfn,
                                                     int4* __restrict__ ovf,
                                                     const float* __restrict__ W_fp,
                                                     const float* __restrict__ W_rt,
                                                     const float* __restrict__ W_pp,
                                                     unsigned short* __restrict__ Bp_fp,
                                                     unsigned short* __restrict__ Bp_fin) {
    int b = blockIdx.x;
    if (b < 512) {                                // fill cf
        int p = b & 3;
        int blk = b >> 2;
        int rlo = p * 100000, rhi = rlo + 100000;
        int tid0 = (blk * 256 + (int)threadIdx.x) * 4;
        fill_fixed(src_cf, dst_cf, ea_cf, E_CF, rlo, rhi, CAP_CF,
                   tid0, 128 * 256 * 4, cnt_cf, pe_cf, ovfn, ovf);
    } else if (b < 560) {                         // pack W_fp: 48 blocks
        int t = (b - 512) * 256 + threadIdx.x;    // 12288
        int j = t & 7, lane = (t >> 3) & 63, ct = (t >> 9) & 7, ks = t >> 12;
        int k = ks * 32 + ((lane >> 4) & 3) * 8 + j;
        int col = ct * 16 + (lane & 15);
        Bp_fp[t] = f2bf(W_fp[k * 128 + col]);
    } else {                                      // pack fin: 128 blocks
        int t = (b - 560) * 256 + threadIdx.x;    // 32768
        int j = t & 7, lane = (t >> 3) & 63, ct = (t >> 9) & 7, ks = t >> 12;
        int k = ks * 32 + ((lane >> 4) & 3) * 8 + j;   // 0..255
        int col = ct * 16 + (lane & 15);
        float v = (k < 128) ? W_rt[k * 128 + col] : W_pp[(k - 128) * 128 + col];
        Bp_fin[t] = f2bf(v);
    }
}

// ======== MEGA: fill_fp ∥ fill_pp ∥ gather8_tf ========
__global__ __launch_bounds__(256) void k_mega(const int* __restrict__ src_fp,
                                              const int* __restrict__ dst_fp,
                                              const float* __restrict__ ea_fp,
                                              const int* __restrict__ src_pp,
                                              const int* __restrict__ dst_pp,
                                              const float* __restrict__ ea_pp,
                                              int* __restrict__ cnt_fp,
                                              int2* __restrict__ pe_fp,
                                              int* __restrict__ cnt_pp,
                                              int2* __restrict__ pe_pp,
                                              int* __restrict__ ovfn,
                                              int4* __restrict__ ovf_fp,
                                              int4* __restrict__ ovf_pp,
                                              const float* __restrict__ xc,
                                              const int* __restrict__ cnt_cf,
                                              const int2* __restrict__ pe_cf,
                                              const int* __restrict__ ovfn_cf,
                                              const int4* __restrict__ ovf_cf,
                                              const float* __restrict__ x_face,
                                              const float* __restrict__ W,
                                              const float* __restrict__ bvec,
                                              unsigned short* __restrict__ yfp) {
    __shared__ float Ws[512];
    __shared__ float bs[64];
    int b = blockIdx.x;
    if (b < 512) {                                // ---- fill fp (4 partitions) ----
        int p = b & 3;
        int blk = b >> 2;
        int rlo = p * 50000, rhi = rlo + 50000;
        int tid0 = (blk * 256 + (int)threadIdx.x) * 4;
        fill_fixed(src_fp, dst_fp, ea_fp, E_FP, rlo, rhi, CAP_FP,
                   tid0, 128 * 256 * 4, cnt_fp, pe_fp, ovfn + 1, ovf_fp);
        return;
    }
    if (b < 1024) {                               // ---- fill pp ----
        int bb = b - 512;
        int p = bb & 3;
        int blk = bb >> 2;
        int rlo = p * 50000, rhi = rlo + 50000;
        int tid0 = (blk * 256 + (int)threadIdx.x) * 4;
        fill_fixed(src_pp, dst_pp, ea_pp, E_PP, rlo, rhi, CAP_PP,
                   tid0, 128 * 256 * 4, cnt_pp, pe_pp, ovfn + 2, ovf_pp);
        return;
    }
    // ---- gather8_tf: one thread per face row ----
    for (int i = threadIdx.x; i < 512; i += 256) Ws[i] = W[i];
    if (threadIdx.x < 64) bs[threadIdx.x] = bvec[threadIdx.x];
    __syncthreads();
    int r = (b - 1024) * 256 + threadIdx.x;
    if (r >= N_FACES) return;
    int n = cnt_cf[r]; if (n > CAP_CF) n = CAP_CF;
    const int2* prow = pe_cf + (size_t)r * CAP_CF;
    float a[8] = {};
    int e = 0;
    for (; e + 1 < n; e += 2) {
        int2 q0 = prow[e], q1 = prow[e + 1];
        float w0 = __int_as_float(q0.y), w1 = __int_as_float(q1.y);
        const float* p0 = xc + (size_t)q0.x * 8;
        const float* p1 = xc + (size_t)q1.x * 8;
        float4 u0 = *(const float4*)p0, u1 = *(const float4*)(p0 + 4);
        float4 v0 = *(const float4*)p1, v1 = *(const float4*)(p1 + 4);
        a[0] += w0 * u0.x + w1 * v0.x; a[1] += w0 * u0.y + w1 * v0.y;
        a[2] += w0 * u0.z + w1 * v0.z; a[3] += w0 * u0.w + w1 * v0.w;
        a[4] += w0 * u1.x + w1 * v1.x; a[5] += w0 * u1.y + w1 * v1.y;
        a[6] += w0 * u1.z + w1 * v1.z; a[7] += w0 * u1.w + w1 * v1.w;
    }
    if (e < n) {
        int2 q0 = prow[e];
        float w0 = __int_as_float(q0.y);
        const float* p0 = xc + (size_t)q0.x * 8;
        float4 u0 = *(const float4*)p0, u1 = *(const float4*)(p0 + 4);
        a[0] += w0 * u0.x; a[1] += w0 * u0.y; a[2] += w0 * u0.z; a[3] += w0 * u0.w;
        a[4] += w0 * u1.x; a[5] += w0 * u1.y; a[6] += w0 * u1.z; a[7] += w0 * u1.w;
    }
    int no = *ovfn_cf;
    if (no > 0) {
        if (no > OVF_CAP) no = OVF_CAP;
        for (int i = 0; i < no; ++i) {
            int4 o = ovf_cf[i];
            if (o.x == r) {
                float w0 = __int_as_float(o.z);
                const float* p0 = xc + (size_t)o.y * 8;
#pragma unroll
                for (int k = 0; k < 8; ++k) a[k] += w0 * p0[k];
            }
        }
    }
    unsigned short* orow = yfp + (size_t)r * 96;
#pragma unroll
    for (int c4 = 0; c4 < 4; ++c4) {
        int j0 = c4 * 16;
        float acc[16];
#pragma unroll
        for (int i = 0; i < 16; ++i) acc[i] = bs[j0 + i];
#pragma unroll
        for (int k = 0; k < 8; ++k) {
            float x = a[k];
            const float* wr = Ws + k * 64 + j0;
#pragma unroll
            for (int i = 0; i < 16; ++i) acc[i] += x * wr[i];
        }
        u16x8 o0, o1;
#pragma unroll
        for (int i = 0; i < 8; ++i) { o0[i] = f2bf(acc[i]); o1[i] = f2bf(acc[8 + i]); }
        *(u16x8*)(orow + j0) = o0;
        *(u16x8*)(orow + j0 + 8) = o1;
    }
    float4 xf0 = *(const float4*)(x_face + (size_t)r * 8);
    float4 xf1 = *(const float4*)(x_face + (size_t)r * 8 + 4);
    u16x8 xo;
    xo[0] = f2bf(xf0.x); xo[1] = f2bf(xf0.y); xo[2] = f2bf(xf0.z); xo[3] = f2bf(xf0.w);
    xo[4] = f2bf(xf1.x); xo[5] = f2bf(xf1.y); xo[6] = f2bf(xf1.z); xo[7] = f2bf(xf1.w);
    *(u16x8*)(orow + 64) = xo;
}

// ======== FUSED: gather96 (32 rows -> LDS) + mfma96 -> y_ptb ========
__global__ __launch_bounds__(256) void k_g96_mfma(const unsigned short* __restrict__ feat,
                                                  const int* __restrict__ cnt,
                                                  const int2* __restrict__ pe,
                                                  const int* __restrict__ ovfn,
                                                  const int4* __restrict__ ovf,
                                                  const unsigned short* __restrict__ Bp,
                                                  const float* __restrict__ bias,
                                                  unsigned short* __restrict__ O) {
    __shared__ __align__(16) unsigned short Asub[32 * LDA96];
    const int w = threadIdx.x >> 6;
    const int lane = threadIdx.x & 63;
    const int l = lane & 31;
    const int R0 = blockIdx.x * 32;
    // phase 1: each wave gathers 8 rows (2 per pass)
    for (int rr = 0; rr < 4; ++rr) {
        int row = R0 + w * 8 + rr * 2 + (lane >> 5);
        int n = cnt[row]; if (n > CAP_FP) n = CAP_FP;
        const int2* prow = pe + (size_t)row * CAP_FP;
        float a0 = 0.f, a1 = 0.f, a2 = 0.f;
        int e = 0;
        for (; e + 3 < n; e += 4) {
            int2 q0 = prow[e], q1 = prow[e + 1], q2 = prow[e + 2], q3 = prow[e + 3];
            float w0 = __int_as_float(q0.y), w1 = __int_as_float(q1.y);
            float w2 = __int_as_float(q2.y), w3 = __int_as_float(q3.y);
            const unsigned short* f0 = feat + (size_t)q0.x * 96 + l;
            const unsigned short* f1 = feat + (size_t)q1.x * 96 + l;
            const unsigned short* f2 = feat + (size_t)q2.x * 96 + l;
            const unsigned short* f3 = feat + (size_t)q3.x * 96 + l;
            a0 += w0 * bf2f(f0[0])  + w1 * bf2f(f1[0])  + w2 * bf2f(f2[0])  + w3 * bf2f(f3[0]);
            a1 += w0 * bf2f(f0[32]) + w1 * bf2f(f1[32]) + w2 * bf2f(f2[32]) + w3 * bf2f(f3[32]);
            a2 += w0 * bf2f(f0[64]) + w1 * bf2f(f1[64]) + w2 * bf2f(f2[64]) + w3 * bf2f(f3[64]);
        }
        for (; e < n; ++e) {
            int2 q0 = prow[e];
            float w0 = __int_as_float(q0.y);
            const unsigned short* f0 = feat + (size_t)q0.x * 96 + l;
            a0 += w0 * bf2f(f0[0]); a1 += w0 * bf2f(f0[32]); a2 += w0 * bf2f(f0[64]);
        }
        int no = *ovfn;
        if (no > 0) {
            if (no > OVF_CAP) no = OVF_CAP;
            for (int i = 0; i < no; ++i) {
                int4 o = ovf[i];
                if (o.x == row) {
                    float w0 = __int_as_float(o.z);
                    const unsigned short* f0 = feat + (size_t)o.y * 96 + l;
                    a0 += w0 * bf2f(f0[0]); a1 += w0 * bf2f(f0[32]); a2 += w0 * bf2f(f0[64]);
                }
            }
        }
        int lr = row - R0;
        Asub[lr * LDA96 + l]      = f2bf(a0);
        Asub[lr * LDA96 + 32 + l] = f2bf(a1);
        Asub[lr * LDA96 + 64 + l] = f2bf(a2);
    }
    __syncthreads();
    // phase 2: MFMA (A from LDS)
    const int rg = w >> 1, cg = w & 1;
    bf16x8 bfr[3][4];
#pragma unroll
    for (int ks = 0; ks < 3; ++ks)
#pragma unroll
        for (int c = 0; c < 4; ++c) {
            int ct = cg * 4 + c;
            bfr[ks][c] = *(const bf16x8*)(Bp + ((size_t)(ks * 8 + ct) * 64 + lane) * 8);
        }
    f32x4 acc[4] = {};
    const unsigned short* arow = Asub + (rg * 16 + (lane & 15)) * LDA96 + ((lane >> 4) * 8);
#pragma unroll
    for (int ks = 0; ks < 3; ++ks) {
        bf16x8 af = *(const bf16x8*)(arow + ks * 32);
#pragma unroll
        for (int c = 0; c < 4; ++c)
            acc[c] = __builtin_amdgcn_mfma_f32_16x16x32_bf16(af, bfr[ks][c], acc[c], 0, 0, 0);
    }
    const int row0 = R0 + rg * 16;
    const int rbase = row0 + (lane >> 4) * 4;
#pragma unroll
    for (int c = 0; c < 4; ++c) {
        int gcol = cg * 64 + c * 16 + (lane & 15);
        float bv = bias[gcol];
#pragma unroll
        for (int r = 0; r < 4; ++r)
            O[(size_t)(rbase + r) * 128 + gcol] = f2bf(acc[c][r] + bv);
    }
}

// ======== FUSED: gather128pp (32 rows -> LDS) + mfma_fin -> out ========
__global__ __launch_bounds__(256) void k_gpp_fin(const unsigned short* __restrict__ feat,
                                                 const int* __restrict__ cnt,
                                                 const int2* __restrict__ pe,
                                                 const int* __restrict__ ovfn,
                                                 const int4* __restrict__ ovf,
                                                 const unsigned short* __restrict__ A1,
                                                 const unsigned short* __restrict__ Bp,
                                                 const float* __restrict__ bias,
                                                 float* __restrict__ out) {
    __shared__ __align__(16) unsigned short Asub[32 * LDA128];
    const int w = threadIdx.x >> 6;
    const int lane = threadIdx.x & 63;
    const int l = lane & 31;
    const int R0 = blockIdx.x * 32;
    for (int rr = 0; rr < 4; ++rr) {
        int row = R0 + w * 8 + rr * 2 + (lane >> 5);
        int n = cnt[row]; if (n > CAP_PP) n = CAP_PP;
        const int2* prow = pe + (size_t)row * CAP_PP;
        float a0 = 0.f, a1 = 0.f, a2 = 0.f, a3 = 0.f;
        int e = 0;
        for (; e + 3 < n; e += 4) {
            int2 q0 = prow[e], q1 = prow[e + 1], q2 = prow[e + 2], q3 = prow[e + 3];
            float w0 = __int_as_float(q0.y), w1 = __int_as_float(q1.y);
            float w2 = __int_as_float(q2.y), w3 = __int_as_float(q3.y);
            const unsigned short* f0 = feat + ((size_t)q0.x << 7) + l;
            const unsigned short* f1 = feat + ((size_t)q1.x << 7) + l;
            const unsigned short* f2 = feat + ((size_t)q2.x << 7) + l;
            const unsigned short* f3 = feat + ((size_t)q3.x << 7) + l;
            a0 += w0 * bf2f(f0[0])  + w1 * bf2f(f1[0])  + w2 * bf2f(f2[0])  + w3 * bf2f(f3[0]);
            a1 += w0 * bf2f(f0[32]) + w1 * bf2f(f1[32]) + w2 * bf2f(f2[32]) + w3 * bf2f(f3[32]);
            a2 += w0 * bf2f(f0[64]) + w1 * bf2f(f1[64]) + w2 * bf2f(f2[64]) + w3 * bf2f(f3[64]);
            a3 += w0 * bf2f(f0[96]) + w1 * bf2f(f1[96]) + w2 * bf2f(f2[96]) + w3 * bf2f(f3[96]);
        }
        for (; e < n; ++e) {
            int2 q0 = prow[e];
            float w0 = __int_as_float(q0.y);
            const unsigned short* f0 = feat + ((size_t)q0.x << 7) + l;
            a0 += w0 * bf2f(f0[0]);  a1 += w0 * bf2f(f0[32]);
            a2 += w0 * bf2f(f0[64]); a3 += w0 * bf2f(f0[96]);
        }
        int no = *ovfn;
        if (no > 0) {
            if (no > OVF_CAP) no = OVF_CAP;
            for (int i = 0; i < no; ++i) {
                int4 o = ovf[i];
                if (o.x == row) {
                    float w0 = __int_as_float(o.z);
                    const unsigned short* f0 = feat + ((size_t)o.y << 7) + l;
                    a0 += w0 * bf2f(f0[0]);  a1 += w0 * bf2f(f0[32]);
                    a2 += w0 * bf2f(f0[64]); a3 += w0 * bf2f(f0[96]);
                }
            }
        }
        int lr = row - R0;
        Asub[lr * LDA128 + l]      = f2bf(a0);
        Asub[lr * LDA128 + 32 + l] = f2bf(a1);
        Asub[lr * LDA128 + 64 + l] = f2bf(a2);
        Asub[lr * LDA128 + 96 + l] = f2bf(a3);
    }
    __syncthreads();
    const int rg = w >> 1, cg = w & 1;
    bf16x8 bfr[8][4];
#pragma unroll
    for (int ks = 0; ks < 8; ++ks)
#pragma unroll
        for (int c = 0; c < 4; ++c) {
            int ct = cg * 4 + c;
            bfr[ks][c] = *(const bf16x8*)(Bp + ((size_t)(ks * 8 + ct) * 64 + lane) * 8);
        }
    f32x4 acc[4] = {};
    const unsigned short* a1p = A1 + (size_t)(R0 + rg * 16 + (lane & 15)) * 128 + ((lane >> 4) * 8);
    const unsigned short* a2p = Asub + (rg * 16 + (lane & 15)) * LDA128 + ((lane >> 4) * 8);
#pragma unroll
    for (int ks = 0; ks < 4; ++ks) {
        bf16x8 af = *(const bf16x8*)(a1p + ks * 32);
#pragma unroll
        for (int c = 0; c < 4; ++c)
            acc[c] = __builtin_amdgcn_mfma_f32_16x16x32_bf16(af, bfr[ks][c], acc[c], 0, 0, 0);
    }
#pragma unroll
    for (int ks = 0; ks < 4; ++ks) {
        bf16x8 af = *(const bf16x8*)(a2p + ks * 32);
#pragma unroll
        for (int c = 0; c < 4; ++c)
            acc[c] = __builtin_amdgcn_mfma_f32_16x16x32_bf16(af, bfr[ks + 4][c], acc[c], 0, 0, 0);
    }
    const int row0 = R0 + rg * 16;
    const int rbase = row0 + (lane >> 4) * 4;
#pragma unroll
    for (int c = 0; c < 4; ++c) {
        int gcol = cg * 64 + c * 16 + (lane & 15);
        float bv = bias[gcol];
#pragma unroll
        for (int r = 0; r < 4; ++r)
            out[(size_t)(rbase + r) * 128 + gcol] = acc[c][r] + bv;
    }
}

extern "C" void kernel_launch(void* const* d_in, const int* in_sizes, int n_in,
                              void* d_out, int out_size, void* d_ws, size_t ws_size,
                              hipStream_t stream) {
    const float* x_centers = (const float*)d_in[0];
    const float* x_face    = (const float*)d_in[1];
    const float* W_cf      = (const float*)d_in[2];
    const float* b_cf      = (const float*)d_in[3];
    const float* W_fp      = (const float*)d_in[4];
    const float* b_fp      = (const float*)d_in[5];
    const float* W_pp      = (const float*)d_in[6];
    const float* W_rt      = (const float*)d_in[7];
    const float* b_pp      = (const float*)d_in[8];
    const float* ea_cf     = (const float*)d_in[9];
    const float* ea_fp     = (const float*)d_in[10];
    const float* ea_pp     = (const float*)d_in[11];
    const int* src_cf      = (const int*)d_in[12];
    const int* dst_cf      = (const int*)d_in[13];
    const int* src_fp      = (const int*)d_in[14];
    const int* dst_fp      = (const int*)d_in[15];
    const int* src_pp      = (const int*)d_in[16];
    const int* dst_pp      = (const int*)d_in[17];
    float* out = (float*)d_out;

    char* ws = (char*)d_ws;
    unsigned short* yfp    = (unsigned short*)(ws + 0);           // bf16 [400k][96]  76.8MB
    unsigned short* y_ptb  = (unsigned short*)(ws + 80000000);    // bf16 [200k][128] 51.2MB (own region)
    int2* pe_fp            = (int2*)(ws + 132000000);             // 38.4MB
    int2* pe_cf            = (int2*)(ws + 172000000);             // 51.2MB
    int2* pe_pp            = (int2*)(ws + 224000000);             // 51.2MB
    int*  cnt_cf           = (int*)(ws + 280000000);              // 400k ints
    int*  cnt_fp           = (int*)(ws + 281600000);              // 200k
    int*  cnt_pp           = (int*)(ws + 282400000);              // 200k
    int*  ovfn             = (int*)(ws + 283200000);              // 4 ints (memset-covered)
    int4* ovf_cf           = (int4*)(ws + 284000000);             // 64KB
    int4* ovf_fp           = (int4*)(ws + 284100000);
    int4* ovf_pp           = (int4*)(ws + 284200000);
    unsigned short* Bp_fp  = (unsigned short*)(ws + 284300000);   // 24KB
    unsigned short* Bp_fin = (unsigned short*)(ws + 284400000);   // 64KB

    // zero counters (cnt_cf..ovfn contiguous) in one async memset
    hipMemsetAsync(cnt_cf, 0, 3200016, stream);
    // fill cf + weight packs
    k_fillcf_pack<<<688, 256, 0, stream>>>(src_cf, dst_cf, ea_cf, cnt_cf, pe_cf, ovfn, ovf_cf,
                                           W_fp, W_rt, W_pp, Bp_fp, Bp_fin);
    // MEGA: fill fp + fill pp + gather8_tf
    k_mega<<<1024 + 1563, 256, 0, stream>>>(src_fp, dst_fp, ea_fp, src_pp, dst_pp, ea_pp,
                                            cnt_fp, pe_fp, cnt_pp, pe_pp, ovfn, ovf_fp, ovf_pp,
                                            x_centers, cnt_cf, pe_cf, ovfn, ovf_cf,
                                            x_face, W_cf, b_cf, yfp);
    // fused faces->points gather + MFMA -> y_ptb
    k_g96_mfma<<<6250, 256, 0, stream>>>(yfp, cnt_fp, pe_fp, ovfn + 1, ovf_fp, Bp_fp, b_fp, y_ptb);
    // fused points->points gather + final MFMA -> out
    k_gpp_fin<<<6250, 256, 0, stream>>>(y_ptb, cnt_pp, pe_pp, ovfn + 2, ovf_pp, y_ptb, Bp_fin, b_pp, out);
}

// Round 14
// 389.404 us; speedup vs baseline: 3.0204x; 1.0229x over previous
//
#include <hip/hip_runtime.h>
#include <hip/hip_bf16.h>

#define N_CELLS  200000
#define N_FACES  400000
#define N_POINTS 200000
#define E_CF     800000
#define E_FP     800000
#define E_PP     1200000
#define CAP_CF   16
#define CAP_FP   24
#define CAP_PP   32
#define OVF_CAP  4096
#define LDA96    104      // LDS stride (elems): 16B-aligned rows, ~2-way banks
#define LDA128   136

typedef __attribute__((ext_vector_type(8))) short bf16x8;
typedef __attribute__((ext_vector_type(8))) unsigned short u16x8;
typedef __attribute__((ext_vector_type(4))) float f32x4;

__device__ __forceinline__ float bf2f(unsigned short u) {
    union { unsigned int i; float f; } v; v.i = ((unsigned int)u) << 16; return v.f;
}
__device__ __forceinline__ unsigned short f2bf(float f) {
    __hip_bfloat16 h = __float2bfloat16(f);
    return *reinterpret_cast<unsigned short*>(&h);
}

// ======== fixed-stride fill helper (partitioned sweep) ========
__device__ __forceinline__ void fill_fixed(const int* __restrict__ src,
                                           const int* __restrict__ dst,
                                           const float* __restrict__ ea,
                                           int nE, int rlo, int rhi, int cap,
                                           int tid0, int stride,
                                           int* __restrict__ cnt,
                                           int2* __restrict__ pe,
                                           int* __restrict__ ovfn,
                                           int4* __restrict__ ovf) {
    for (int e = tid0; e < nE; e += stride) {
        int4 d4 = *(const int4*)(dst + e);
        int4 s4 = *(const int4*)(src + e);
        float4 w4 = *(const float4*)(ea + e);
        int dd[4] = {d4.x, d4.y, d4.z, d4.w};
        int ss[4] = {s4.x, s4.y, s4.z, s4.w};
        float ww[4] = {w4.x, w4.y, w4.z, w4.w};
#pragma unroll
        for (int i = 0; i < 4; ++i) {
            int d = dd[i];
            if (d >= rlo && d < rhi) {
                int t = atomicAdd(&cnt[d], 1);
                if (t < cap)
                    pe[(size_t)d * cap + t] = make_int2(ss[i], __float_as_int(ww[i]));
                else {
                    int g = atomicAdd(ovfn, 1);
                    if (g < OVF_CAP) ovf[g] = make_int4(d, ss[i], __float_as_int(ww[i]), 0);
                }
            }
        }
    }
}

// ======== LAUNCH A: fill_cf ∥ fill_fp ∥ weight packs ========
__global__ __launch_bounds__(256) void k_fillA(const int* __restrict__ src_cf,
                                               const int* __restrict__ dst_cf,
                                               const float* __restrict__ ea_cf,
                                               int* __restrict__ cnt_cf,
                                               int2* __restrict__ pe_cf,
                                               const int* __restrict__ src_fp,
                                               const int* __restrict__ dst_fp,
                                               const float* __restrict__ ea_fp,
                                               int* __restrict__ cnt_fp,
                                               int2* __restrict__ pe_fp,
                                               int* __restrict__ ovfn,
                                               int4* __restrict__ ovf_cf,
                                               int4* __restrict__ ovf_fp,
                                               const float* __restrict__ W_fp,
                                               const float* __restrict__ W_rt,
                                               const float* __restrict__ W_pp,
                                               unsigned short* __restrict__ Bp_fp,
                                               unsigned short* __restrict__ Bp_fin) {
    int b = blockIdx.x;
    if (b < 512) {                                // fill cf (4 partitions x 128 blocks)
        int p = b & 3;
        int blk = b >> 2;
        int rlo = p * 100000, rhi = rlo + 100000;
        int tid0 = (blk * 256 + (int)threadIdx.x) * 4;
        fill_fixed(src_cf, dst_cf, ea_cf, E_CF, rlo, rhi, CAP_CF,
                   tid0, 128 * 256 * 4, cnt_cf, pe_cf, ovfn, ovf_cf);
    } else if (b < 1024) {                        // fill fp
        int bb = b - 512;
        int p = bb & 3;
        int blk = bb >> 2;
        int rlo = p * 50000, rhi = rlo + 50000;
        int tid0 = (blk * 256 + (int)threadIdx.x) * 4;
        fill_fixed(src_fp, dst_fp, ea_fp, E_FP, rlo, rhi, CAP_FP,
                   tid0, 128 * 256 * 4, cnt_fp, pe_fp, ovfn + 1, ovf_fp);
    } else if (b < 1072) {                        // pack W_fp: 48 blocks
        int t = (b - 1024) * 256 + threadIdx.x;   // 12288
        int j = t & 7, lane = (t >> 3) & 63, ct = (t >> 9) & 7, ks = t >> 12;
        int k = ks * 32 + ((lane >> 4) & 3) * 8 + j;
        int col = ct * 16 + (lane & 15);
        Bp_fp[t] = f2bf(W_fp[k * 128 + col]);
    } else {                                      // pack fin: 128 blocks
        int t = (b - 1072) * 256 + threadIdx.x;   // 32768
        int j = t & 7, lane = (t >> 3) & 63, ct = (t >> 9) & 7, ks = t >> 12;
        int k = ks * 32 + ((lane >> 4) & 3) * 8 + j;   // 0..255
        int col = ct * 16 + (lane & 15);
        float v = (k < 128) ? W_rt[k * 128 + col] : W_pp[(k - 128) * 128 + col];
        Bp_fin[t] = f2bf(v);
    }
}

// ======== LAUNCH B: fill_pp ∥ gather8_tf ========
__global__ __launch_bounds__(256) void k_fillB(const int* __restrict__ src_pp,
                                               const int* __restrict__ dst_pp,
                                               const float* __restrict__ ea_pp,
                                               int* __restrict__ cnt_pp,
                                               int2* __restrict__ pe_pp,
                                               int* __restrict__ ovfn,
                                               int4* __restrict__ ovf_pp,
                                               const float* __restrict__ xc,
                                               const int* __restrict__ cnt_cf,
                                               const int2* __restrict__ pe_cf,
                                               const int* __restrict__ ovfn_cf,
                                               const int4* __restrict__ ovf_cf,
                                               const float* __restrict__ x_face,
                                               const float* __restrict__ W,
                                               const float* __restrict__ bvec,
                                               unsigned short* __restrict__ yfp) {
    __shared__ float Ws[512];
    __shared__ float bs[64];
    int b = blockIdx.x;
    if (b < 512) {                                // ---- fill pp ----
        int p = b & 3;
        int blk = b >> 2;
        int rlo = p * 50000, rhi = rlo + 50000;
        int tid0 = (blk * 256 + (int)threadIdx.x) * 4;
        fill_fixed(src_pp, dst_pp, ea_pp, E_PP, rlo, rhi, CAP_PP,
                   tid0, 128 * 256 * 4, cnt_pp, pe_pp, ovfn + 2, ovf_pp);
        return;
    }
    // ---- gather8_tf: one thread per face row ----
    for (int i = threadIdx.x; i < 512; i += 256) Ws[i] = W[i];
    if (threadIdx.x < 64) bs[threadIdx.x] = bvec[threadIdx.x];
    __syncthreads();
    int r = (b - 512) * 256 + threadIdx.x;
    if (r >= N_FACES) return;
    int n = cnt_cf[r]; if (n > CAP_CF) n = CAP_CF;
    const int2* prow = pe_cf + (size_t)r * CAP_CF;
    float a[8] = {};
    int e = 0;
    for (; e + 1 < n; e += 2) {
        int2 q0 = prow[e], q1 = prow[e + 1];
        float w0 = __int_as_float(q0.y), w1 = __int_as_float(q1.y);
        const float* p0 = xc + (size_t)q0.x * 8;
        const float* p1 = xc + (size_t)q1.x * 8;
        float4 u0 = *(const float4*)p0, u1 = *(const float4*)(p0 + 4);
        float4 v0 = *(const float4*)p1, v1 = *(const float4*)(p1 + 4);
        a[0] += w0 * u0.x + w1 * v0.x; a[1] += w0 * u0.y + w1 * v0.y;
        a[2] += w0 * u0.z + w1 * v0.z; a[3] += w0 * u0.w + w1 * v0.w;
        a[4] += w0 * u1.x + w1 * v1.x; a[5] += w0 * u1.y + w1 * v1.y;
        a[6] += w0 * u1.z + w1 * v1.z; a[7] += w0 * u1.w + w1 * v1.w;
    }
    if (e < n) {
        int2 q0 = prow[e];
        float w0 = __int_as_float(q0.y);
        const float* p0 = xc + (size_t)q0.x * 8;
        float4 u0 = *(const float4*)p0, u1 = *(const float4*)(p0 + 4);
        a[0] += w0 * u0.x; a[1] += w0 * u0.y; a[2] += w0 * u0.z; a[3] += w0 * u0.w;
        a[4] += w0 * u1.x; a[5] += w0 * u1.y; a[6] += w0 * u1.z; a[7] += w0 * u1.w;
    }
    int no = *ovfn_cf;
    if (no > 0) {
        if (no > OVF_CAP) no = OVF_CAP;
        for (int i = 0; i < no; ++i) {
            int4 o = ovf_cf[i];
            if (o.x == r) {
                float w0 = __int_as_float(o.z);
                const float* p0 = xc + (size_t)o.y * 8;
#pragma unroll
                for (int k = 0; k < 8; ++k) a[k] += w0 * p0[k];
            }
        }
    }
    unsigned short* orow = yfp + (size_t)r * 96;
#pragma unroll
    for (int c4 = 0; c4 < 4; ++c4) {
        int j0 = c4 * 16;
        float acc[16];
#pragma unroll
        for (int i = 0; i < 16; ++i) acc[i] = bs[j0 + i];
#pragma unroll
        for (int k = 0; k < 8; ++k) {
            float x = a[k];
            const float* wr = Ws + k * 64 + j0;
#pragma unroll
            for (int i = 0; i < 16; ++i) acc[i] += x * wr[i];
        }
        u16x8 o0, o1;
#pragma unroll
        for (int i = 0; i < 8; ++i) { o0[i] = f2bf(acc[i]); o1[i] = f2bf(acc[8 + i]); }
        *(u16x8*)(orow + j0) = o0;
        *(u16x8*)(orow + j0 + 8) = o1;
    }
    float4 xf0 = *(const float4*)(x_face + (size_t)r * 8);
    float4 xf1 = *(const float4*)(x_face + (size_t)r * 8 + 4);
    u16x8 xo;
    xo[0] = f2bf(xf0.x); xo[1] = f2bf(xf0.y); xo[2] = f2bf(xf0.z); xo[3] = f2bf(xf0.w);
    xo[4] = f2bf(xf1.x); xo[5] = f2bf(xf1.y); xo[6] = f2bf(xf1.z); xo[7] = f2bf(xf1.w);
    *(u16x8*)(orow + 64) = xo;
}

// ======== FUSED: gather96 (32 rows -> LDS) + mfma96 -> y_ptb ========
__global__ __launch_bounds__(256) void k_g96_mfma(const unsigned short* __restrict__ feat,
                                                  const int* __restrict__ cnt,
                                                  const int2* __restrict__ pe,
                                                  const int* __restrict__ ovfn,
                                                  const int4* __restrict__ ovf,
                                                  const unsigned short* __restrict__ Bp,
                                                  const float* __restrict__ bias,
                                                  unsigned short* __restrict__ O) {
    __shared__ __align__(16) unsigned short Asub[32 * LDA96];
    const int w = threadIdx.x >> 6;
    const int lane = threadIdx.x & 63;
    const int l = lane & 31;
    const int R0 = blockIdx.x * 32;
    for (int rr = 0; rr < 4; ++rr) {
        int row = R0 + w * 8 + rr * 2 + (lane >> 5);
        int n = cnt[row]; if (n > CAP_FP) n = CAP_FP;
        const int2* prow = pe + (size_t)row * CAP_FP;
        float a0 = 0.f, a1 = 0.f, a2 = 0.f;
        int e = 0;
        for (; e + 3 < n; e += 4) {
            int2 q0 = prow[e], q1 = prow[e + 1], q2 = prow[e + 2], q3 = prow[e + 3];
            float w0 = __int_as_float(q0.y), w1 = __int_as_float(q1.y);
            float w2 = __int_as_float(q2.y), w3 = __int_as_float(q3.y);
            const unsigned short* f0 = feat + (size_t)q0.x * 96 + l;
            const unsigned short* f1 = feat + (size_t)q1.x * 96 + l;
            const unsigned short* f2 = feat + (size_t)q2.x * 96 + l;
            const unsigned short* f3 = feat + (size_t)q3.x * 96 + l;
            a0 += w0 * bf2f(f0[0])  + w1 * bf2f(f1[0])  + w2 * bf2f(f2[0])  + w3 * bf2f(f3[0]);
            a1 += w0 * bf2f(f0[32]) + w1 * bf2f(f1[32]) + w2 * bf2f(f2[32]) + w3 * bf2f(f3[32]);
            a2 += w0 * bf2f(f0[64]) + w1 * bf2f(f1[64]) + w2 * bf2f(f2[64]) + w3 * bf2f(f3[64]);
        }
        for (; e < n; ++e) {
            int2 q0 = prow[e];
            float w0 = __int_as_float(q0.y);
            const unsigned short* f0 = feat + (size_t)q0.x * 96 + l;
            a0 += w0 * bf2f(f0[0]); a1 += w0 * bf2f(f0[32]); a2 += w0 * bf2f(f0[64]);
        }
        int no = *ovfn;
        if (no > 0) {
            if (no > OVF_CAP) no = OVF_CAP;
            for (int i = 0; i < no; ++i) {
                int4 o = ovf[i];
                if (o.x == row) {
                    float w0 = __int_as_float(o.z);
                    const unsigned short* f0 = feat + (size_t)o.y * 96 + l;
                    a0 += w0 * bf2f(f0[0]); a1 += w0 * bf2f(f0[32]); a2 += w0 * bf2f(f0[64]);
                }
            }
        }
        int lr = row - R0;
        Asub[lr * LDA96 + l]      = f2bf(a0);
        Asub[lr * LDA96 + 32 + l] = f2bf(a1);
        Asub[lr * LDA96 + 64 + l] = f2bf(a2);
    }
    __syncthreads();
    const int rg = w >> 1, cg = w & 1;
    bf16x8 bfr[3][4];
#pragma unroll
    for (int ks = 0; ks < 3; ++ks)
#pragma unroll
        for (int c = 0; c < 4; ++c) {
            int ct = cg * 4 + c;
            bfr[ks][c] = *(const bf16x8*)(Bp + ((size_t)(ks * 8 + ct) * 64 + lane) * 8);
        }
    f32x4 acc[4] = {};
    const unsigned short* arow = Asub + (rg * 16 + (lane & 15)) * LDA96 + ((lane >> 4) * 8);
#pragma unroll
    for (int ks = 0; ks < 3; ++ks) {
        bf16x8 af = *(const bf16x8*)(arow + ks * 32);
#pragma unroll
        for (int c = 0; c < 4; ++c)
            acc[c] = __builtin_amdgcn_mfma_f32_16x16x32_bf16(af, bfr[ks][c], acc[c], 0, 0, 0);
    }
    const int row0 = R0 + rg * 16;
    const int rbase = row0 + (lane >> 4) * 4;
#pragma unroll
    for (int c = 0; c < 4; ++c) {
        int gcol = cg * 64 + c * 16 + (lane & 15);
        float bv = bias[gcol];
#pragma unroll
        for (int r = 0; r < 4; ++r)
            O[(size_t)(rbase + r) * 128 + gcol] = f2bf(acc[c][r] + bv);
    }
}

// ======== FUSED: gather128pp (32 rows -> LDS) + mfma_fin -> out ========
__global__ __launch_bounds__(256) void k_gpp_fin(const unsigned short* __restrict__ feat,
                                                 const int* __restrict__ cnt,
                                                 const int2* __restrict__ pe,
                                                 const int* __restrict__ ovfn,
                                                 const int4* __restrict__ ovf,
                                                 const unsigned short* __restrict__ A1,
                                                 const unsigned short* __restrict__ Bp,
                                                 const float* __restrict__ bias,
                                                 float* __restrict__ out) {
    __shared__ __align__(16) unsigned short Asub[32 * LDA128];
    const int w = threadIdx.x >> 6;
    const int lane = threadIdx.x & 63;
    const int l = lane & 31;
    const int R0 = blockIdx.x * 32;
    for (int rr = 0; rr < 4; ++rr) {
        int row = R0 + w * 8 + rr * 2 + (lane >> 5);
        int n = cnt[row]; if (n > CAP_PP) n = CAP_PP;
        const int2* prow = pe + (size_t)row * CAP_PP;
        float a0 = 0.f, a1 = 0.f, a2 = 0.f, a3 = 0.f;
        int e = 0;
        for (; e + 3 < n; e += 4) {
            int2 q0 = prow[e], q1 = prow[e + 1], q2 = prow[e + 2], q3 = prow[e + 3];
            float w0 = __int_as_float(q0.y), w1 = __int_as_float(q1.y);
            float w2 = __int_as_float(q2.y), w3 = __int_as_float(q3.y);
            const unsigned short* f0 = feat + ((size_t)q0.x << 7) + l;
            const unsigned short* f1 = feat + ((size_t)q1.x << 7) + l;
            const unsigned short* f2 = feat + ((size_t)q2.x << 7) + l;
            const unsigned short* f3 = feat + ((size_t)q3.x << 7) + l;
            a0 += w0 * bf2f(f0[0])  + w1 * bf2f(f1[0])  + w2 * bf2f(f2[0])  + w3 * bf2f(f3[0]);
            a1 += w0 * bf2f(f0[32]) + w1 * bf2f(f1[32]) + w2 * bf2f(f2[32]) + w3 * bf2f(f3[32]);
            a2 += w0 * bf2f(f0[64]) + w1 * bf2f(f1[64]) + w2 * bf2f(f2[64]) + w3 * bf2f(f3[64]);
            a3 += w0 * bf2f(f0[96]) + w1 * bf2f(f1[96]) + w2 * bf2f(f2[96]) + w3 * bf2f(f3[96]);
        }
        for (; e < n; ++e) {
            int2 q0 = prow[e];
            float w0 = __int_as_float(q0.y);
            const unsigned short* f0 = feat + ((size_t)q0.x << 7) + l;
            a0 += w0 * bf2f(f0[0]);  a1 += w0 * bf2f(f0[32]);
            a2 += w0 * bf2f(f0[64]); a3 += w0 * bf2f(f0[96]);
        }
        int no = *ovfn;
        if (no > 0) {
            if (no > OVF_CAP) no = OVF_CAP;
            for (int i = 0; i < no; ++i) {
                int4 o = ovf[i];
                if (o.x == row) {
                    float w0 = __int_as_float(o.z);
                    const unsigned short* f0 = feat + ((size_t)o.y << 7) + l;
                    a0 += w0 * bf2f(f0[0]);  a1 += w0 * bf2f(f0[32]);
                    a2 += w0 * bf2f(f0[64]); a3 += w0 * bf2f(f0[96]);
                }
            }
        }
        int lr = row - R0;
        Asub[lr * LDA128 + l]      = f2bf(a0);
        Asub[lr * LDA128 + 32 + l] = f2bf(a1);
        Asub[lr * LDA128 + 64 + l] = f2bf(a2);
        Asub[lr * LDA128 + 96 + l] = f2bf(a3);
    }
    __syncthreads();
    const int rg = w >> 1, cg = w & 1;
    bf16x8 bfr[8][4];
#pragma unroll
    for (int ks = 0; ks < 8; ++ks)
#pragma unroll
        for (int c = 0; c < 4; ++c) {
            int ct = cg * 4 + c;
            bfr[ks][c] = *(const bf16x8*)(Bp + ((size_t)(ks * 8 + ct) * 64 + lane) * 8);
        }
    f32x4 acc[4] = {};
    const unsigned short* a1p = A1 + (size_t)(R0 + rg * 16 + (lane & 15)) * 128 + ((lane >> 4) * 8);
    const unsigned short* a2p = Asub + (rg * 16 + (lane & 15)) * LDA128 + ((lane >> 4) * 8);
#pragma unroll
    for (int ks = 0; ks < 4; ++ks) {
        bf16x8 af = *(const bf16x8*)(a1p + ks * 32);
#pragma unroll
        for (int c = 0; c < 4; ++c)
            acc[c] = __builtin_amdgcn_mfma_f32_16x16x32_bf16(af, bfr[ks][c], acc[c], 0, 0, 0);
    }
#pragma unroll
    for (int ks = 0; ks < 4; ++ks) {
        bf16x8 af = *(const bf16x8*)(a2p + ks * 32);
#pragma unroll
        for (int c = 0; c < 4; ++c)
            acc[c] = __builtin_amdgcn_mfma_f32_16x16x32_bf16(af, bfr[ks + 4][c], acc[c], 0, 0, 0);
    }
    const int row0 = R0 + rg * 16;
    const int rbase = row0 + (lane >> 4) * 4;
#pragma unroll
    for (int c = 0; c < 4; ++c) {
        int gcol = cg * 64 + c * 16 + (lane & 15);
        float bv = bias[gcol];
#pragma unroll
        for (int r = 0; r < 4; ++r)
            out[(size_t)(rbase + r) * 128 + gcol] = acc[c][r] + bv;
    }
}

extern "C" void kernel_launch(void* const* d_in, const int* in_sizes, int n_in,
                              void* d_out, int out_size, void* d_ws, size_t ws_size,
                              hipStream_t stream) {
    const float* x_centers = (const float*)d_in[0];
    const float* x_face    = (const float*)d_in[1];
    const float* W_cf      = (const float*)d_in[2];
    const float* b_cf      = (const float*)d_in[3];
    const float* W_fp      = (const float*)d_in[4];
    const float* b_fp      = (const float*)d_in[5];
    const float* W_pp      = (const float*)d_in[6];
    const float* W_rt      = (const float*)d_in[7];
    const float* b_pp      = (const float*)d_in[8];
    const float* ea_cf     = (const float*)d_in[9];
    const float* ea_fp     = (const float*)d_in[10];
    const float* ea_pp     = (const float*)d_in[11];
    const int* src_cf      = (const int*)d_in[12];
    const int* dst_cf      = (const int*)d_in[13];
    const int* src_fp      = (const int*)d_in[14];
    const int* dst_fp      = (const int*)d_in[15];
    const int* src_pp      = (const int*)d_in[16];
    const int* dst_pp      = (const int*)d_in[17];
    float* out = (float*)d_out;

    char* ws = (char*)d_ws;
    unsigned short* yfp    = (unsigned short*)(ws + 0);           // bf16 [400k][96]  76.8MB
    unsigned short* y_ptb  = (unsigned short*)(ws + 80000000);    // bf16 [200k][128] 51.2MB
    int2* pe_fp            = (int2*)(ws + 132000000);             // 38.4MB
    int2* pe_cf            = (int2*)(ws + 172000000);             // 51.2MB
    int2* pe_pp            = (int2*)(ws + 224000000);             // 51.2MB
    int*  cnt_cf           = (int*)(ws + 280000000);              // 400k ints
    int*  cnt_fp           = (int*)(ws + 281600000);              // 200k
    int*  cnt_pp           = (int*)(ws + 282400000);              // 200k
    int*  ovfn             = (int*)(ws + 283200000);              // 4 ints (memset-covered)
    int4* ovf_cf           = (int4*)(ws + 284000000);             // 64KB
    int4* ovf_fp           = (int4*)(ws + 284100000);
    int4* ovf_pp           = (int4*)(ws + 284200000);
    unsigned short* Bp_fp  = (unsigned short*)(ws + 284300000);   // 24KB
    unsigned short* Bp_fin = (unsigned short*)(ws + 284400000);   // 64KB

    // zero counters (cnt_cf..ovfn contiguous) in one async memset
    hipMemsetAsync(cnt_cf, 0, 3200016, stream);
    // LAUNCH A: fill_cf ∥ fill_fp ∥ weight packs
    k_fillA<<<1200, 256, 0, stream>>>(src_cf, dst_cf, ea_cf, cnt_cf, pe_cf,
                                      src_fp, dst_fp, ea_fp, cnt_fp, pe_fp,
                                      ovfn, ovf_cf, ovf_fp,
                                      W_fp, W_rt, W_pp, Bp_fp, Bp_fin);
    // LAUNCH B: fill_pp ∥ gather8_tf
    k_fillB<<<512 + 1563, 256, 0, stream>>>(src_pp, dst_pp, ea_pp, cnt_pp, pe_pp,
                                            ovfn, ovf_pp,
                                            x_centers, cnt_cf, pe_cf, ovfn, ovf_cf,
                                            x_face, W_cf, b_cf, yfp);
    // LAUNCH C: fused faces->points gather + MFMA -> y_ptb
    k_g96_mfma<<<6250, 256, 0, stream>>>(yfp, cnt_fp, pe_fp, ovfn + 1, ovf_fp, Bp_fp, b_fp, y_ptb);
    // LAUNCH D: fused points->points gather + final MFMA -> out
    k_gpp_fin<<<6250, 256, 0, stream>>>(y_ptb, cnt_pp, pe_pp, ovfn + 2, ovf_pp, y_ptb, Bp_fin, b_pp, out);
}